// Round 13
// baseline (2163.501 us; speedup 1.0000x reference)
//
#include <hip/hip_runtime.h>
#include <hip/hip_bf16.h>
#include <cstddef>
#include <cstdint>

// Problem dims
#define NB 32
#define RR 512
#define SL 513
#define EE 512

typedef short short8 __attribute__((ext_vector_type(8)));
typedef unsigned short ushort8v __attribute__((ext_vector_type(8)));
typedef unsigned short ushort4v __attribute__((ext_vector_type(4)));
typedef float f32x4 __attribute__((ext_vector_type(4)));

constexpr int OP_NONE = 0, OP_GELU = 1, OP_ADDTO = 2;

__device__ __forceinline__ float gelu_f(float x) {
  return 0.5f * x * (1.0f + erff(x * 0.7071067811865475f));
}
__device__ __forceinline__ float bf2f(unsigned short u) {
  return __uint_as_float(((unsigned)u) << 16);
}
__device__ __forceinline__ unsigned short f2bf(float f) {
  unsigned u = __float_as_uint(f);
  u += 0x7FFFu + ((u >> 16) & 1u);
  return (unsigned short)(u >> 16);
}
// async global->LDS, 16B per lane; lds must be wave-uniform base (lane*16 added by HW)
__device__ __forceinline__ void gl2lds16(const unsigned short* g, unsigned short* l) {
  __builtin_amdgcn_global_load_lds(
      (const __attribute__((address_space(1))) unsigned int*)(const void*)g,
      (__attribute__((address_space(3))) unsigned int*)(void*)l, 16, 0, 0);
}
// bijective XCD-chunked block-id remap (m204): consecutive nid -> same XCD
__device__ __forceinline__ int xcd_remap(int bid, int nwg) {
  int q = nwg >> 3, r = nwg & 7;
  int xcd = bid & 7, off = bid >> 3;
  return (xcd < r ? xcd * (q + 1) : r * (q + 1) + (xcd - r) * q) + off;
}

// ---------------- mask dtype detection (bool ambiguity hedge) ----------------
__global__ void detect_mask_kernel(const unsigned int* __restrict__ mask,
                                   int* __restrict__ flag) {
  __shared__ int notint, notfloat;
  if (threadIdx.x == 0) { notint = 0; notfloat = 0; }
  __syncthreads();
  for (int i = threadIdx.x; i < 4096; i += 256) {
    unsigned int v = mask[i];
    if (v > 1u) notint = 1;
    if (v != 0u && v != 0x3F800000u) notfloat = 1;
  }
  __syncthreads();
  if (threadIdx.x == 0) {
    int f = 2;
    if (!notint) f = 0;
    else if (!notfloat) f = 1;
    *flag = f;
  }
}

__global__ void convert_mask_kernel(const void* __restrict__ mask,
                                    const int* __restrict__ flag,
                                    int* __restrict__ mout) {
  int i = blockIdx.x * 256 + threadIdx.x;
  if (i >= NB * RR) return;
  int f = *flag;
  int v;
  if (f == 0)      v = (((const int*)mask)[i] != 0);
  else if (f == 1) v = (((const unsigned int*)mask)[i] != 0u);
  else             v = (((const unsigned char*)mask)[i] != 0);
  mout[i] = v;
}

// ---------------- zero counters ----------------
__global__ void zeroi_kernel(int* __restrict__ p, int n) {
  int i = threadIdx.x;
  for (; i < n; i += 256) p[i] = 0;
}

// ---------------- fp32 -> bf16 conversion ----------------
__global__ __launch_bounds__(256) void f2bf_kernel(
    const float* __restrict__ s, unsigned short* __restrict__ d, int n) {
  int i = (blockIdx.x * 256 + threadIdx.x) * 4;
  if (i + 3 < n) {
    float4 v = *reinterpret_cast<const float4*>(s + i);
    d[i] = f2bf(v.x); d[i + 1] = f2bf(v.y);
    d[i + 2] = f2bf(v.z); d[i + 3] = f2bf(v.w);
  } else {
    for (; i < n; ++i) d[i] = f2bf(s[i]);
  }
}

// ---- batched weight convert: 5 segments [pw;f1;f2;pkw;pvw] -> contiguous ----
__global__ __launch_bounds__(256) void f2bfw_kernel(
    const float* __restrict__ pw, const float* __restrict__ f1,
    const float* __restrict__ f2, const float* __restrict__ pkw,
    const float* __restrict__ pvw, unsigned short* __restrict__ dst) {
  int i = (blockIdx.x * 256 + threadIdx.x) * 4;
  if (i >= 14680064) return;
  const float* src;
  if (i < 1572864)        src = pw  + i;
  else if (i < 7864320)   src = f1  + (i - 1572864);
  else if (i < 14155776)  src = f2  + (i - 7864320);
  else if (i < 14417920)  src = pkw + (i - 14155776);
  else                    src = pvw + (i - 14417920);
  float4 v = *reinterpret_cast<const float4*>(src);
  dst[i] = f2bf(v.x); dst[i + 1] = f2bf(v.y);
  dst[i + 2] = f2bf(v.z); dst[i + 3] = f2bf(v.w);
}

// ---- fused QKV weight concat+convert: dst[l][768][512], rows = [q;k;v] ----
__global__ __launch_bounds__(256) void f2bf_qkv_kernel(
    const float* __restrict__ qw, const float* __restrict__ kw,
    const float* __restrict__ vw, unsigned short* __restrict__ dst) {
  int idx = (blockIdx.x * 256 + threadIdx.x) * 4;
  if (idx >= 6 * 768 * 512) return;
  int l = idx / (768 * 512);
  int rem = idx - l * 768 * 512;
  int row = rem >> 9, col = rem & 511;
  const float* src;
  if (row < 512)      src = qw + ((size_t)l * 512 + row) * 512 + col;
  else if (row < 640) src = kw + ((size_t)l * 128 + (row - 512)) * 512 + col;
  else                src = vw + ((size_t)l * 128 + (row - 640)) * 512 + col;
  float4 v = *reinterpret_cast<const float4*>(src);
  dst[idx] = f2bf(v.x); dst[idx + 1] = f2bf(v.y);
  dst[idx + 2] = f2bf(v.z); dst[idx + 3] = f2bf(v.w);
}

// ---------------- global-feature embedding: X[b,0,:] (+ bf16 shadow) -------
__global__ __launch_bounds__(256) void gemb_kernel(
    const int* __restrict__ mask, const float* __restrict__ steps,
    const float* __restrict__ temp, const float* __restrict__ mc,
    const float* __restrict__ gw, const float* __restrict__ gb,
    float* __restrict__ X, unsigned short* __restrict__ Xb) {
  const int b = blockIdx.y, e0 = blockIdx.x * 64;
  const int tid = threadIdx.x;
  __shared__ float gd[516];
  gd[tid]       = (float)mask[b * RR + tid];
  gd[tid + 256] = (float)mask[b * RR + tid + 256];
  if (tid == 0) {
    gd[512] = steps[b] * (1.0f / 512.0f);
    gd[513] = logf(temp[b]);
    gd[514] = mc[b];
  }
  __syncthreads();
  const int e = e0 + (tid >> 2), q = tid & 3;
  const float* w = gw + (size_t)e * 515;
  const int j0 = q * 129;
  const int j1 = (j0 + 129 < 515) ? j0 + 129 : 515;
  float acc = 0.f;
  for (int j = j0; j < j1; ++j) acc += gd[j] * w[j];
  acc += __shfl_xor(acc, 1);
  acc += __shfl_xor(acc, 2);
  if (q == 0) {
    float v = acc + gb[e];
    X[(size_t)b * SL * EE + e] = v;
    Xb[(size_t)b * SL * EE + e] = f2bf(v);
  }
}

// ---------------- room rows: X[b,1+r,:] (+ bf16 shadow) ----------------
__global__ __launch_bounds__(128) void buildx_kernel(
    const int* __restrict__ mask, const int* __restrict__ rpx,
    const int* __restrict__ rpy, const int* __restrict__ hx,
    const int* __restrict__ hy, const float* __restrict__ pex,
    const float* __restrict__ pey, const float* __restrict__ remb,
    const float* __restrict__ uemb, float* __restrict__ X,
    unsigned short* __restrict__ Xb) {
  const int r = blockIdx.x, b = blockIdx.y;
  const int e = threadIdx.x * 4;
  float4 v;
  if (mask[b * RR + r]) {
    int ix = rpx[b * RR + r] + hx[r];
    int iy = rpy[b * RR + r] + hy[r];
    float4 a = *reinterpret_cast<const float4*>(pex + (size_t)ix * EE + e);
    float4 c = *reinterpret_cast<const float4*>(pey + (size_t)iy * EE + e);
    float4 d = *reinterpret_cast<const float4*>(remb + (size_t)r * EE + e);
    v = make_float4(a.x + c.x + d.x, a.y + c.y + d.y, a.z + c.z + d.z,
                    a.w + c.w + d.w);
  } else {
    v = *reinterpret_cast<const float4*>(uemb + (size_t)r * EE + e);
  }
  size_t off = ((size_t)b * SL + r + 1) * EE + e;
  *reinterpret_cast<float4*>(X + off) = v;
  ushort4v bv = {f2bf(v.x), f2bf(v.y), f2bf(v.z), f2bf(v.w)};
  *reinterpret_cast<ushort4v*>(Xb + off) = bv;
}

// ---- bf16 MFMA GEMM: BK=64, T2 XOR-swizzle + bijective XCD block remap ----
template <int OP, bool WF32, bool WBF16>
__global__ __launch_bounds__(256) void bgemm_kernel(
    const unsigned short* __restrict__ A, const unsigned short* __restrict__ B,
    float* __restrict__ Cf, unsigned short* __restrict__ Cb,
    int M, int N, int K, int lda, int ldb) {
  __shared__ unsigned short As[128 * 64];
  __shared__ unsigned short Bs[128 * 64];
  const int tid = threadIdx.x;
  const int wv = tid >> 6, l = tid & 63;
  const int wm0 = (wv >> 1) * 64, wn0 = (wv & 1) * 64;
  const int nid = xcd_remap(blockIdx.y * gridDim.x + blockIdx.x,
                            gridDim.x * gridDim.y);
  const int m0 = (nid / gridDim.x) * 128, n0 = (nid % gridDim.x) * 128;
  const int lrow = l & 15, lg = l >> 4;
  const int srow = l >> 3;
  const int scol = ((l & 7) ^ srow) * 8;
  const unsigned short* Ag = A + (size_t)(m0 + wv * 32 + srow) * lda + scol;
  const unsigned short* Bg = B + (size_t)(n0 + wv * 32 + srow) * ldb + scol;
  unsigned short* Al = As + (wv * 32) * 64;
  unsigned short* Bl = Bs + (wv * 32) * 64;

  f32x4 acc[4][4] = {};
  for (int k0 = 0; k0 < K; k0 += 64) {
    __syncthreads();
#pragma unroll
    for (int c = 0; c < 4; ++c) {
      gl2lds16(Ag + (size_t)(c * 8) * lda + k0, Al + c * 8 * 64);
      gl2lds16(Bg + (size_t)(c * 8) * ldb + k0, Bl + c * 8 * 64);
    }
    __syncthreads();
#pragma unroll
    for (int ks = 0; ks < 2; ++ks) {
      const int cidx = ((ks << 5) | (lg << 3)) ^ ((lrow & 7) << 3);
      short8 af[4], bfr[4];
#pragma unroll
      for (int i = 0; i < 4; ++i)
        af[i] = *reinterpret_cast<const short8*>(
            &As[(wm0 + i * 16 + lrow) * 64 + cidx]);
#pragma unroll
      for (int j = 0; j < 4; ++j)
        bfr[j] = *reinterpret_cast<const short8*>(
            &Bs[(wn0 + j * 16 + lrow) * 64 + cidx]);
#pragma unroll
      for (int i = 0; i < 4; ++i)
#pragma unroll
        for (int j = 0; j < 4; ++j)
          acc[i][j] = __builtin_amdgcn_mfma_f32_16x16x32_bf16(
              af[i], bfr[j], acc[i][j], 0, 0, 0);
    }
  }
#pragma unroll
  for (int i = 0; i < 4; ++i) {
#pragma unroll
    for (int r = 0; r < 4; ++r) {
      int m = m0 + wm0 + i * 16 + (l >> 4) * 4 + r;
      if (m < M) {
        size_t ro = (size_t)m * N;
#pragma unroll
        for (int j = 0; j < 4; ++j) {
          int n = n0 + wn0 + j * 16 + lrow;
          float v = acc[i][j][r];
          if (OP == OP_GELU) v = gelu_f(v);
          if (OP == OP_ADDTO) v += Cf[ro + n];
          if (WF32) Cf[ro + n] = v;
          if (WBF16) Cb[ro + n] = f2bf(v);
        }
      }
    }
  }
}

// ------- fused QKV GEMM (BK=64 swizzled): A[M,512] x Wqkv[768,512]^T -------
// Q pre-scaled by 0.125*log2(e) so attention softmax runs in exp2 domain.
__global__ __launch_bounds__(256) void bgemm_qkv_kernel(
    const unsigned short* __restrict__ A, const unsigned short* __restrict__ B,
    unsigned short* __restrict__ Q, unsigned short* __restrict__ Kq,
    unsigned short* __restrict__ Vq, int M) {
  __shared__ unsigned short As[128 * 64];
  __shared__ unsigned short Bs[128 * 64];
  const int tid = threadIdx.x;
  const int wv = tid >> 6, l = tid & 63;
  const int wm0 = (wv >> 1) * 64, wn0 = (wv & 1) * 64;
  const int nid = xcd_remap(blockIdx.y * gridDim.x + blockIdx.x,
                            gridDim.x * gridDim.y);
  const int m0 = (nid / gridDim.x) * 128;
  const int bx = nid % gridDim.x;
  const int n0 = bx * 128;
  const int lrow = l & 15, lg = l >> 4;
  const int srow = l >> 3;
  const int scol = ((l & 7) ^ srow) * 8;
  const unsigned short* Ag = A + (size_t)(m0 + wv * 32 + srow) * 512 + scol;
  const unsigned short* Bg = B + (size_t)(n0 + wv * 32 + srow) * 512 + scol;
  unsigned short* Al = As + (wv * 32) * 64;
  unsigned short* Bl = Bs + (wv * 32) * 64;

  f32x4 acc[4][4] = {};
  for (int k0 = 0; k0 < 512; k0 += 64) {
    __syncthreads();
#pragma unroll
    for (int c = 0; c < 4; ++c) {
      gl2lds16(Ag + (size_t)(c * 8) * 512 + k0, Al + c * 8 * 64);
      gl2lds16(Bg + (size_t)(c * 8) * 512 + k0, Bl + c * 8 * 64);
    }
    __syncthreads();
#pragma unroll
    for (int ks = 0; ks < 2; ++ks) {
      const int cidx = ((ks << 5) | (lg << 3)) ^ ((lrow & 7) << 3);
      short8 af[4], bfr[4];
#pragma unroll
      for (int i = 0; i < 4; ++i)
        af[i] = *reinterpret_cast<const short8*>(
            &As[(wm0 + i * 16 + lrow) * 64 + cidx]);
#pragma unroll
      for (int j = 0; j < 4; ++j)
        bfr[j] = *reinterpret_cast<const short8*>(
            &Bs[(wn0 + j * 16 + lrow) * 64 + cidx]);
#pragma unroll
      for (int i = 0; i < 4; ++i)
#pragma unroll
        for (int j = 0; j < 4; ++j)
          acc[i][j] = __builtin_amdgcn_mfma_f32_16x16x32_bf16(
              af[i], bfr[j], acc[i][j], 0, 0, 0);
    }
  }
  unsigned short* Co;
  int ldc, cbase;
  float scl;
  if (bx < 4)      { Co = Q;  ldc = 512; cbase = bx * 128; scl = 0.1803368801f; }
  else if (bx == 4){ Co = Kq; ldc = 128; cbase = 0;        scl = 1.0f;   }
  else             { Co = Vq; ldc = 128; cbase = 0;        scl = 1.0f;   }
#pragma unroll
  for (int i = 0; i < 4; ++i) {
#pragma unroll
    for (int r = 0; r < 4; ++r) {
      int m = m0 + wm0 + i * 16 + lg * 4 + r;
      if (m < M) {
#pragma unroll
        for (int j = 0; j < 4; ++j) {
          int n = cbase + wn0 + j * 16 + lrow;
          Co[(size_t)m * ldc + n] = f2bf(acc[i][j][r] * scl);
        }
      }
    }
  }
}

// ---- V transpose: [b*SL+t][128] -> Vt[(b*2+g)*64+d][544], chunk per block --
__global__ __launch_bounds__(256) void vtrans_kernel(
    const unsigned short* __restrict__ Vp, unsigned short* __restrict__ Vt) {
  const int g = blockIdx.x, b = blockIdx.y, t0 = blockIdx.z * 64;
  const int tid = threadIdx.x;
  __shared__ unsigned short T[64][72];
  const int tr = tid >> 2, c4 = (tid & 3) * 16;
  const int d = tid >> 2, tc = (tid & 3) * 16;
  int t = t0 + tr;
  ushort8v v0 = {}, v1 = {};
  if (t < SL) {
    const unsigned short* src = Vp + ((size_t)b * SL + t) * 128 + g * 64 + c4;
    v0 = *reinterpret_cast<const ushort8v*>(src);
    v1 = *reinterpret_cast<const ushort8v*>(src + 8);
  }
  *reinterpret_cast<ushort8v*>(&T[tr][c4]) = v0;
  *reinterpret_cast<ushort8v*>(&T[tr][c4 + 8]) = v1;
  __syncthreads();
  if (t0 + tc < 544) {
    unsigned short tmp[16];
#pragma unroll
    for (int i = 0; i < 16; ++i) tmp[i] = T[tc + i][d];
    unsigned short* dst = Vt + ((size_t)((b * 2 + g) * 64) + d) * 544 + t0 + tc;
    *reinterpret_cast<ushort8v*>(dst) = *reinterpret_cast<ushort8v*>(tmp);
    *reinterpret_cast<ushort8v*>(dst + 8) = *reinterpret_cast<ushort8v*>(tmp + 8);
  }
}

// --- MFMA flash attention: block (qt64, g, b) with XCD-locality remap,
// --- 4 waves (wave=head), exp2 softmax + defer-max, VGPR 84 (6 waves/SIMD).
__global__ __launch_bounds__(256, 2) void attn_mfma_kernel(
    const unsigned short* __restrict__ Qb, const unsigned short* __restrict__ Kb,
    const unsigned short* __restrict__ Vt, unsigned short* __restrict__ Ab) {
  const int lin = (blockIdx.z * gridDim.y + blockIdx.y) * gridDim.x + blockIdx.x;
  const int nid = xcd_remap(lin, 9 * 2 * NB);
  const int qt = nid % 9, g = (nid / 9) & 1, b = nid / 18;
  const int tid = threadIdx.x;
  const int w = tid >> 6, l = tid & 63;
  const int l15 = l & 15, lg = l >> 4;
  const int h = g * 4 + w;
  const int s0 = qt * 64;

  __shared__ unsigned short Plds[4][64][40];  // per-wave slice, stride 40

  short8 qf[4][2];
#pragma unroll
  for (int sf = 0; sf < 4; ++sf)
#pragma unroll
    for (int ks = 0; ks < 2; ++ks)
      qf[sf][ks] = *reinterpret_cast<const short8*>(
          Qb + ((size_t)b * SL + s0 + sf * 16 + l15) * 512 + h * 64 + ks * 32 + lg * 8);

  f32x4 Oacc[4][4] = {};
  float mrun[4] = {-1e30f, -1e30f, -1e30f, -1e30f};
  float lrun[4] = {0.f, 0.f, 0.f, 0.f};

  const size_t krow0 = (size_t)b * SL;
  const size_t vrow0 = (size_t)((b * 2 + g) * 64);

  for (int t0 = 0; t0 < 544; t0 += 32) {
    short8 kf[2][2];
#pragma unroll
    for (int tf = 0; tf < 2; ++tf)
#pragma unroll
      for (int ks = 0; ks < 2; ++ks)
        kf[tf][ks] = *reinterpret_cast<const short8*>(
            Kb + (krow0 + t0 + tf * 16 + l15) * 128 + g * 64 + ks * 32 + lg * 8);

    f32x4 Sacc[2][4] = {};
    __builtin_amdgcn_s_setprio(1);
#pragma unroll
    for (int tf = 0; tf < 2; ++tf)
#pragma unroll
      for (int sf = 0; sf < 4; ++sf) {
        Sacc[tf][sf] = __builtin_amdgcn_mfma_f32_16x16x32_bf16(
            kf[tf][0], qf[sf][0], Sacc[tf][sf], 0, 0, 0);
        Sacc[tf][sf] = __builtin_amdgcn_mfma_f32_16x16x32_bf16(
            kf[tf][1], qf[sf][1], Sacc[tf][sf], 0, 0, 0);
      }
    __builtin_amdgcn_s_setprio(0);

    if (t0 + 32 > SL) {  // mask t >= SL
#pragma unroll
      for (int tf = 0; tf < 2; ++tf)
#pragma unroll
        for (int sf = 0; sf < 4; ++sf)
#pragma unroll
          for (int r = 0; r < 4; ++r) {
            int t = t0 + tf * 16 + lg * 4 + r;
            Sacc[tf][sf][r] = (t < SL) ? Sacc[tf][sf][r] : -1e30f;
          }
    }

#pragma unroll
    for (int sf = 0; sf < 4; ++sf) {
      float pm = Sacc[0][sf][0];
#pragma unroll
      for (int r = 1; r < 4; ++r) pm = fmaxf(pm, Sacc[0][sf][r]);
#pragma unroll
      for (int r = 0; r < 4; ++r) pm = fmaxf(pm, Sacc[1][sf][r]);
      // defer-max (exp2 domain): rescale only when a row max grew past mrun+8
      if (!__all(pm <= mrun[sf] + 8.0f)) {
        float pmx = fmaxf(pm, __shfl_xor(pm, 16));
        pmx = fmaxf(pmx, __shfl_xor(pmx, 32));
        float mnew = fmaxf(mrun[sf], pmx);
        float rsc = exp2f(mrun[sf] - mnew);
        mrun[sf] = mnew;
        lrun[sf] *= rsc;
#pragma unroll
        for (int r = 0; r < 4; ++r) {
          float f = __shfl(rsc, lg * 4 + r);
#pragma unroll
          for (int df = 0; df < 4; ++df) Oacc[sf][df][r] *= f;
        }
      }
      const float mcur = mrun[sf];
      float ps = 0.f;
      float p[2][4];
#pragma unroll
      for (int tf = 0; tf < 2; ++tf)
#pragma unroll
        for (int r = 0; r < 4; ++r) {
          float e = exp2f(Sacc[tf][sf][r] - mcur);
          p[tf][r] = e;
          ps += e;
        }
      ps += __shfl_xor(ps, 16);
      ps += __shfl_xor(ps, 32);
      lrun[sf] += ps;
      const int srow = sf * 16 + l15;
#pragma unroll
      for (int tf = 0; tf < 2; ++tf) {
        unsigned pk0, pk1;
        asm("v_cvt_pk_bf16_f32 %0, %1, %2" : "=v"(pk0) : "v"(p[tf][0]), "v"(p[tf][1]));
        asm("v_cvt_pk_bf16_f32 %0, %1, %2" : "=v"(pk1) : "v"(p[tf][2]), "v"(p[tf][3]));
        unsigned* dst = reinterpret_cast<unsigned*>(&Plds[w][srow][tf * 16 + lg * 4]);
        dst[0] = pk0;
        dst[1] = pk1;
      }
    }

    short8 pa[4], vb[4];
#pragma unroll
    for (int mf = 0; mf < 4; ++mf)
      pa[mf] = *reinterpret_cast<const short8*>(&Plds[w][mf * 16 + l15][lg * 8]);
#pragma unroll
    for (int df = 0; df < 4; ++df)
      vb[df] = *reinterpret_cast<const short8*>(
          Vt + (vrow0 + df * 16 + l15) * 544 + t0 + lg * 8);
    __builtin_amdgcn_s_setprio(1);
#pragma unroll
    for (int mf = 0; mf < 4; ++mf)
#pragma unroll
      for (int df = 0; df < 4; ++df)
        Oacc[mf][df] = __builtin_amdgcn_mfma_f32_16x16x32_bf16(
            pa[mf], vb[df], Oacc[mf][df], 0, 0, 0);
    __builtin_amdgcn_s_setprio(0);
  }

#pragma unroll
  for (int sf = 0; sf < 4; ++sf) {
#pragma unroll
    for (int r = 0; r < 4; ++r) {
      float lr = __shfl(lrun[sf], lg * 4 + r);
      float inv = 1.0f / lr;
      int s = s0 + sf * 16 + lg * 4 + r;
      if (s < SL) {
        unsigned short* op = Ab + ((size_t)b * SL + s) * 512 + h * 64;
#pragma unroll
        for (int df = 0; df < 4; ++df)
          op[df * 16 + l15] = f2bf(Oacc[sf][df][r] * inv);
      }
    }
  }
}

// -------- attention pooling head: block per (h, b), KV = [M][1024] K|V ------
__global__ __launch_bounds__(256) void pool_kernel(
    const unsigned short* __restrict__ KV, const float* __restrict__ poolq,
    float* __restrict__ P) {
  const int h = blockIdx.x, b = blockIdx.y, tid = threadIdx.x;
  __shared__ float sc[SL];
  __shared__ float red[256];
  __shared__ float pqs[64];
  if (tid < 64) pqs[tid] = poolq[h * 64 + tid];
  __syncthreads();
  float tmax = -1e30f;
  for (int t = tid; t < SL; t += 256) {
    const ushort8v* kp = reinterpret_cast<const ushort8v*>(
        KV + ((size_t)(b * SL + t)) * 1024 + h * 64);
    float acc = 0.f;
#pragma unroll
    for (int c = 0; c < 8; ++c) {
      ushort8v v = kp[c];
#pragma unroll
      for (int j = 0; j < 8; ++j) acc += pqs[c * 8 + j] * bf2f(v[j]);
    }
    float s = acc * 0.125f;
    sc[t] = s;
    tmax = fmaxf(tmax, s);
  }
  red[tid] = tmax;
  __syncthreads();
  for (int off = 128; off >= 1; off >>= 1) {
    if (tid < off) red[tid] = fmaxf(red[tid], red[tid + off]);
    __syncthreads();
  }
  float mh = red[0];
  __syncthreads();
  float tsum = 0.f;
  for (int t = tid; t < SL; t += 256) {
    float e = __expf(sc[t] - mh);
    sc[t] = e;
    tsum += e;
  }
  red[tid] = tsum;
  __syncthreads();
  for (int off = 128; off >= 1; off >>= 1) {
    if (tid < off) red[tid] += red[tid + off];
    __syncthreads();
  }
  float inv = 1.0f / red[0];
  __syncthreads();
  const int d = tid & 63, tc = tid >> 6;
  float acc = 0.f;
  for (int t = tc; t < SL; t += 4)
    acc += sc[t] * bf2f(KV[((size_t)(b * SL + t)) * 1024 + 512 + h * 64 + d]);
  red[tid] = acc;
  __syncthreads();
  if (tid < 64) {
    float s = red[tid] + red[tid + 64] + red[tid + 128] + red[tid + 192];
    P[(size_t)b * 512 + h * 64 + tid] = s * inv;
  }
}

// ---- split-K skinny GEMM (M=32) with deterministic fan-in reduce ----
// grid (N/64, KC). Partials -> Cp[kc][32][N]; last block per n-tile (device
// atomics + fences) reduces in FIXED kc order and applies epilogue OP.
template <int OP>
__global__ __launch_bounds__(256) void skgemm_kernel(
    const float* __restrict__ A, const float* __restrict__ B,
    float* __restrict__ Cp, float* __restrict__ C, int* __restrict__ cnt,
    int N, int K, int KC) {
  const int n0 = blockIdx.x * 64, kc = blockIdx.y, k0 = kc * 64;
  const int tid = threadIdx.x;
  __shared__ float As[32][68];
  __shared__ float Rs[4][32][64];
  __shared__ int lastf;
  {
    int r = tid >> 3, c = (tid & 7) * 8;
    float4 v0 = *reinterpret_cast<const float4*>(A + (size_t)r * K + k0 + c);
    float4 v1 = *reinterpret_cast<const float4*>(A + (size_t)r * K + k0 + c + 4);
    *reinterpret_cast<float4*>(&As[r][c]) = v0;
    *reinterpret_cast<float4*>(&As[r][c + 4]) = v1;
  }
  __syncthreads();
  const int n = tid & 63, ks = tid >> 6;
  const float* Brow = B + (size_t)(n0 + n) * K + k0 + ks * 16;
  float bv[16];
#pragma unroll
  for (int kk = 0; kk < 16; ++kk) bv[kk] = Brow[kk];
  float acc[32];
#pragma unroll
  for (int m = 0; m < 32; ++m) acc[m] = 0.f;
#pragma unroll
  for (int kk = 0; kk < 16; ++kk) {
#pragma unroll
    for (int m = 0; m < 32; ++m) acc[m] += As[m][ks * 16 + kk] * bv[kk];
  }
#pragma unroll
  for (int m = 0; m < 32; ++m) Rs[ks][m][n] = acc[m];
  __syncthreads();
  for (int idx = tid; idx < 2048; idx += 256) {
    int m = idx >> 6, nn = idx & 63;
    float s = Rs[0][m][nn] + Rs[1][m][nn] + Rs[2][m][nn] + Rs[3][m][nn];
    Cp[((size_t)kc * 32 + m) * N + n0 + nn] = s;
  }
  // fan-in: last block for this n-tile reduces all KC partials (fixed order)
  __threadfence();
  if (tid == 0) lastf = (atomicAdd(&cnt[blockIdx.x], 1) == KC - 1) ? 1 : 0;
  __syncthreads();
  if (!lastf) return;
  __threadfence();
  for (int idx = tid; idx < 2048; idx += 256) {
    int m = idx >> 6, nn = idx & 63;
    float s = 0.f;
    for (int k = 0; k < KC; ++k)
      s += Cp[((size_t)k * 32 + m) * N + n0 + nn];
    if (OP == OP_GELU) s = gelu_f(s);
    size_t ci = (size_t)m * N + n0 + nn;
    if (OP == OP_ADDTO) s += C[ci];
    C[ci] = s;
  }
}

// ---------------- layernorm over 512, one block per b ----------------
__global__ __launch_bounds__(256) void ln_kernel(float* __restrict__ Xg) {
  const int b = blockIdx.x, tid = threadIdx.x;
  __shared__ float red[256];
  float* x = Xg + (size_t)b * 512;
  float v0 = x[tid], v1 = x[tid + 256];
  red[tid] = v0 + v1;
  __syncthreads();
  for (int off = 128; off >= 1; off >>= 1) {
    if (tid < off) red[tid] += red[tid + off];
    __syncthreads();
  }
  float mu = red[0] * (1.0f / 512.0f);
  __syncthreads();
  float d0 = v0 - mu, d1 = v1 - mu;
  red[tid] = d0 * d0 + d1 * d1;
  __syncthreads();
  for (int off = 128; off >= 1; off >>= 1) {
    if (tid < off) red[tid] += red[tid + off];
    __syncthreads();
  }
  float var = red[0] * (1.0f / 512.0f);
  float inv = 1.0f / sqrtf(var + 1e-5f);
  x[tid] = d0 * inv;
  x[tid + 256] = d1 * inv;
}

extern "C" void kernel_launch(void* const* d_in, const int* in_sizes, int n_in,
                              void* d_out, int out_size, void* d_ws,
                              size_t ws_size, hipStream_t stream) {
  const void*  mask_raw = d_in[0];
  const int*   rpx  = (const int*)d_in[1];
  const int*   rpy  = (const int*)d_in[2];
  const int*   hx   = (const int*)d_in[3];
  const int*   hy   = (const int*)d_in[4];
  const float* steps = (const float*)d_in[5];
  const float* temp  = (const float*)d_in[6];
  const float* mc    = (const float*)d_in[7];
  const float* gw    = (const float*)d_in[8];
  const float* gb    = (const float*)d_in[9];
  const float* pex   = (const float*)d_in[10];
  const float* pey   = (const float*)d_in[11];
  const float* remb  = (const float*)d_in[12];
  const float* uemb  = (const float*)d_in[13];
  const float* qw    = (const float*)d_in[14];
  const float* kw    = (const float*)d_in[15];
  const float* vw    = (const float*)d_in[16];
  const float* pw    = (const float*)d_in[17];
  const float* f1    = (const float*)d_in[18];
  const float* f2    = (const float*)d_in[19];
  const float* pq    = (const float*)d_in[20];
  const float* pkw   = (const float*)d_in[21];
  const float* pvw   = (const float*)d_in[22];
  const float* ppw   = (const float*)d_in[23];
  const float* g1    = (const float*)d_in[24];
  const float* g2    = (const float*)d_in[25];
  const float* ow1   = (const float*)d_in[26];
  const float* ow2   = (const float*)d_in[27];
  float* out = (float*)d_out;
  char*  wsb = (char*)d_ws;

  // byte-offset workspace layout (~128.0 MB), padded rows: 16544
  float*          X   = (float*)(wsb + 0);                   // 16544x512 f32
  unsigned short* Xb  = (unsigned short*)(wsb + 33882112);   // 16544x512 bf16
  unsigned short* QbH = (unsigned short*)(wsb + 50823168);   // Q / FF-hidden-half base
  unsigned short* Kbb = (unsigned short*)(wsb + 67764224);   // K proj (dead during FF)
  unsigned short* VtB = (unsigned short*)(wsb + 71999488);   // Vt (dead during FF)
  unsigned short* Abb = (unsigned short*)(wsb + 76455936);   // V / attn out (dead during FF)
  unsigned short* Wb  = (unsigned short*)(wsb + 93396992);   // bf16 weights
  float*          Pb  = (float*)(wsb + 127475712);
  float*          Xg  = (float*)(wsb + 127541248);
  float*          Gh  = (float*)(wsb + 127606784);
  int*            mint  = (int*)(wsb + 127868928);
  int*            mflag = (int*)(wsb + 127934464);
  int*            cnts  = (int*)(wsb + 127938560);  // 11 x 32 fan-in counters
  float*          Cp  = (float*)QbH;          // split-K partials (after pool)
  unsigned short* Hb  = QbH;                  // FF hidden half / pool-KV: 16544x1024 bf16

  // bf16 weight offsets (ushort elements)
  unsigned short* wqkv = Wb;                  // [6][768][512] fused q;k;v
  unsigned short* wpw  = Wb + 2359296;        // [pw;f1;f2;pkw;pvw] contiguous
  unsigned short* wf1  = Wb + 3932160;
  unsigned short* wf2  = Wb + 10223616;
  unsigned short* wpkv = Wb + 16515072;       // [1024][512] = [pk;pv] (adjacent)

  detect_mask_kernel<<<1, 256, 0, stream>>>((const unsigned int*)mask_raw, mflag);
  convert_mask_kernel<<<64, 256, 0, stream>>>(mask_raw, mflag, mint);
  zeroi_kernel<<<1, 256, 0, stream>>>(cnts, 352);

  f2bf_qkv_kernel<<<2304, 256, 0, stream>>>(qw, kw, vw, wqkv);
  f2bfw_kernel<<<14336, 256, 0, stream>>>(pw, f1, f2, pkw, pvw, wpw);

  gemb_kernel<<<dim3(8, NB), 256, 0, stream>>>(mint, steps, temp, mc, gw, gb, X, Xb);
  buildx_kernel<<<dim3(RR, NB), 128, 0, stream>>>(mint, rpx, rpy, hx, hy, pex,
                                                  pey, remb, uemb, X, Xb);

  const int Mfull = NB * SL;  // 16416
  for (int l = 0; l < 6; ++l) {
    bgemm_qkv_kernel<<<dim3(6, 129), 256, 0, stream>>>(
        Xb, wqkv + (size_t)l * 393216, QbH, Kbb, Abb, Mfull);
    vtrans_kernel<<<dim3(2, NB, 9), 256, 0, stream>>>(Abb, VtB);
    attn_mfma_kernel<<<dim3(9, 2, NB), 256, 0, stream>>>(QbH, Kbb, VtB, Abb);
    bgemm_kernel<OP_ADDTO, true, true><<<dim3(4, 129), 256, 0, stream>>>(
        Abb, wpw + (size_t)l * 262144, X, Xb, Mfull, 512, 512, 512, 512);
    // FF split over hidden dim: two halves of 1024, full-M grids
    for (int hh = 0; hh < 2; ++hh) {
      bgemm_kernel<OP_GELU, false, true><<<dim3(8, 129), 256, 0, stream>>>(
          Xb, wf1 + (size_t)l * 1048576 + (size_t)hh * 1024 * 512, nullptr, Hb,
          Mfull, 1024, 512, 512, 512);
      if (hh == 0)
        bgemm_kernel<OP_ADDTO, true, false><<<dim3(4, 129), 256, 0, stream>>>(
            Hb, wf2 + (size_t)l * 1048576, X, nullptr,
            Mfull, 512, 1024, 1024, 2048);
      else
        bgemm_kernel<OP_ADDTO, true, true><<<dim3(4, 129), 256, 0, stream>>>(
            Hb, wf2 + (size_t)l * 1048576 + 1024, X, Xb,
            Mfull, 512, 1024, 1024, 2048);
    }
  }

  // pooling head: fused K|V projection into Hb [M][1024], then block-per-(h,b)
  bgemm_kernel<OP_NONE, false, true><<<dim3(8, 129), 256, 0, stream>>>(
      Xb, wpkv, nullptr, Hb, Mfull, 1024, 512, 512, 512);
  pool_kernel<<<dim3(8, NB), 256, 0, stream>>>(Hb, pq, Pb);

  // small head MLP stack: split-K skinny GEMMs with fused fan-in reduce
  skgemm_kernel<OP_NONE><<<dim3(8, 8), 256, 0, stream>>>(
      Pb, ppw, Cp, Xg, cnts + 0, 512, 512, 8);
  ln_kernel<<<NB, 256, 0, stream>>>(Xg);
  for (int l = 0; l < 4; ++l) {
    skgemm_kernel<OP_GELU><<<dim3(32, 8), 256, 0, stream>>>(
        Xg, g1 + (size_t)l * 2048 * 512, Cp, Gh, cnts + (1 + 2 * l) * 32,
        2048, 512, 8);
    skgemm_kernel<OP_ADDTO><<<dim3(8, 32), 256, 0, stream>>>(
        Gh, g2 + (size_t)l * 512 * 2048, Cp, Xg, cnts + (2 + 2 * l) * 32,
        512, 2048, 32);
  }
  skgemm_kernel<OP_GELU><<<dim3(32, 8), 256, 0, stream>>>(
      Xg, ow1, Cp, Gh, cnts + 9 * 32, 2048, 512, 8);
  skgemm_kernel<OP_NONE><<<dim3(16, 32), 256, 0, stream>>>(
      Gh, ow2, Cp, out, cnts + 10 * 32, 1024, 2048, 32);
}

// Round 14
// 1784.832 us; speedup vs baseline: 1.2122x; 1.2122x over previous
//
#include <hip/hip_runtime.h>
#include <hip/hip_bf16.h>
#include <cstddef>
#include <cstdint>

// Problem dims
#define NB 32
#define RR 512
#define SL 513
#define EE 512

typedef short short8 __attribute__((ext_vector_type(8)));
typedef unsigned short ushort8v __attribute__((ext_vector_type(8)));
typedef unsigned short ushort4v __attribute__((ext_vector_type(4)));
typedef float f32x4 __attribute__((ext_vector_type(4)));

constexpr int OP_NONE = 0, OP_GELU = 1, OP_ADDTO = 2;

__device__ __forceinline__ float gelu_f(float x) {
  return 0.5f * x * (1.0f + erff(x * 0.7071067811865475f));
}
__device__ __forceinline__ float bf2f(unsigned short u) {
  return __uint_as_float(((unsigned)u) << 16);
}
__device__ __forceinline__ unsigned short f2bf(float f) {
  unsigned u = __float_as_uint(f);
  u += 0x7FFFu + ((u >> 16) & 1u);
  return (unsigned short)(u >> 16);
}
// async global->LDS, 16B per lane; lds must be wave-uniform base (lane*16 added by HW)
__device__ __forceinline__ void gl2lds16(const unsigned short* g, unsigned short* l) {
  __builtin_amdgcn_global_load_lds(
      (const __attribute__((address_space(1))) unsigned int*)(const void*)g,
      (__attribute__((address_space(3))) unsigned int*)(void*)l, 16, 0, 0);
}
// bijective XCD-chunked block-id remap (m204): consecutive nid -> same XCD
__device__ __forceinline__ int xcd_remap(int bid, int nwg) {
  int q = nwg >> 3, r = nwg & 7;
  int xcd = bid & 7, off = bid >> 3;
  return (xcd < r ? xcd * (q + 1) : r * (q + 1) + (xcd - r) * q) + off;
}

// ---------------- mask dtype detection (bool ambiguity hedge) ----------------
__global__ void detect_mask_kernel(const unsigned int* __restrict__ mask,
                                   int* __restrict__ flag) {
  __shared__ int notint, notfloat;
  if (threadIdx.x == 0) { notint = 0; notfloat = 0; }
  __syncthreads();
  for (int i = threadIdx.x; i < 4096; i += 256) {
    unsigned int v = mask[i];
    if (v > 1u) notint = 1;
    if (v != 0u && v != 0x3F800000u) notfloat = 1;
  }
  __syncthreads();
  if (threadIdx.x == 0) {
    int f = 2;
    if (!notint) f = 0;
    else if (!notfloat) f = 1;
    *flag = f;
  }
}

__global__ void convert_mask_kernel(const void* __restrict__ mask,
                                    const int* __restrict__ flag,
                                    int* __restrict__ mout) {
  int i = blockIdx.x * 256 + threadIdx.x;
  if (i >= NB * RR) return;
  int f = *flag;
  int v;
  if (f == 0)      v = (((const int*)mask)[i] != 0);
  else if (f == 1) v = (((const unsigned int*)mask)[i] != 0u);
  else             v = (((const unsigned char*)mask)[i] != 0);
  mout[i] = v;
}

// ---- batched weight convert: 5 segments [pw;f1;f2;pkw;pvw] -> contiguous ----
__global__ __launch_bounds__(256) void f2bfw_kernel(
    const float* __restrict__ pw, const float* __restrict__ f1,
    const float* __restrict__ f2, const float* __restrict__ pkw,
    const float* __restrict__ pvw, unsigned short* __restrict__ dst) {
  int i = (blockIdx.x * 256 + threadIdx.x) * 4;
  if (i >= 14680064) return;
  const float* src;
  if (i < 1572864)        src = pw  + i;
  else if (i < 7864320)   src = f1  + (i - 1572864);
  else if (i < 14155776)  src = f2  + (i - 7864320);
  else if (i < 14417920)  src = pkw + (i - 14155776);
  else                    src = pvw + (i - 14417920);
  float4 v = *reinterpret_cast<const float4*>(src);
  dst[i] = f2bf(v.x); dst[i + 1] = f2bf(v.y);
  dst[i + 2] = f2bf(v.z); dst[i + 3] = f2bf(v.w);
}

// ---- fused QKV weight concat+convert: dst[l][768][512], rows = [q;k;v] ----
__global__ __launch_bounds__(256) void f2bf_qkv_kernel(
    const float* __restrict__ qw, const float* __restrict__ kw,
    const float* __restrict__ vw, unsigned short* __restrict__ dst) {
  int idx = (blockIdx.x * 256 + threadIdx.x) * 4;
  if (idx >= 6 * 768 * 512) return;
  int l = idx / (768 * 512);
  int rem = idx - l * 768 * 512;
  int row = rem >> 9, col = rem & 511;
  const float* src;
  if (row < 512)      src = qw + ((size_t)l * 512 + row) * 512 + col;
  else if (row < 640) src = kw + ((size_t)l * 128 + (row - 512)) * 512 + col;
  else                src = vw + ((size_t)l * 128 + (row - 640)) * 512 + col;
  float4 v = *reinterpret_cast<const float4*>(src);
  dst[idx] = f2bf(v.x); dst[idx + 1] = f2bf(v.y);
  dst[idx + 2] = f2bf(v.z); dst[idx + 3] = f2bf(v.w);
}

// ---------------- global-feature embedding: X[b,0,:] (+ bf16 shadow) -------
__global__ __launch_bounds__(256) void gemb_kernel(
    const int* __restrict__ mask, const float* __restrict__ steps,
    const float* __restrict__ temp, const float* __restrict__ mc,
    const float* __restrict__ gw, const float* __restrict__ gb,
    float* __restrict__ X, unsigned short* __restrict__ Xb) {
  const int b = blockIdx.y, e0 = blockIdx.x * 64;
  const int tid = threadIdx.x;
  __shared__ float gd[516];
  gd[tid]       = (float)mask[b * RR + tid];
  gd[tid + 256] = (float)mask[b * RR + tid + 256];
  if (tid == 0) {
    gd[512] = steps[b] * (1.0f / 512.0f);
    gd[513] = logf(temp[b]);
    gd[514] = mc[b];
  }
  __syncthreads();
  const int e = e0 + (tid >> 2), q = tid & 3;
  const float* w = gw + (size_t)e * 515;
  const int j0 = q * 129;
  const int j1 = (j0 + 129 < 515) ? j0 + 129 : 515;
  float acc = 0.f;
  for (int j = j0; j < j1; ++j) acc += gd[j] * w[j];
  acc += __shfl_xor(acc, 1);
  acc += __shfl_xor(acc, 2);
  if (q == 0) {
    float v = acc + gb[e];
    X[(size_t)b * SL * EE + e] = v;
    Xb[(size_t)b * SL * EE + e] = f2bf(v);
  }
}

// ---------------- room rows: X[b,1+r,:] (+ bf16 shadow) ----------------
__global__ __launch_bounds__(128) void buildx_kernel(
    const int* __restrict__ mask, const int* __restrict__ rpx,
    const int* __restrict__ rpy, const int* __restrict__ hx,
    const int* __restrict__ hy, const float* __restrict__ pex,
    const float* __restrict__ pey, const float* __restrict__ remb,
    const float* __restrict__ uemb, float* __restrict__ X,
    unsigned short* __restrict__ Xb) {
  const int r = blockIdx.x, b = blockIdx.y;
  const int e = threadIdx.x * 4;
  float4 v;
  if (mask[b * RR + r]) {
    int ix = rpx[b * RR + r] + hx[r];
    int iy = rpy[b * RR + r] + hy[r];
    float4 a = *reinterpret_cast<const float4*>(pex + (size_t)ix * EE + e);
    float4 c = *reinterpret_cast<const float4*>(pey + (size_t)iy * EE + e);
    float4 d = *reinterpret_cast<const float4*>(remb + (size_t)r * EE + e);
    v = make_float4(a.x + c.x + d.x, a.y + c.y + d.y, a.z + c.z + d.z,
                    a.w + c.w + d.w);
  } else {
    v = *reinterpret_cast<const float4*>(uemb + (size_t)r * EE + e);
  }
  size_t off = ((size_t)b * SL + r + 1) * EE + e;
  *reinterpret_cast<float4*>(X + off) = v;
  ushort4v bv = {f2bf(v.x), f2bf(v.y), f2bf(v.z), f2bf(v.w)};
  *reinterpret_cast<ushort4v*>(Xb + off) = bv;
}

// ---- bf16 MFMA GEMM: BK=64, T2 XOR-swizzle + bijective XCD block remap ----
template <int OP, bool WF32, bool WBF16>
__global__ __launch_bounds__(256) void bgemm_kernel(
    const unsigned short* __restrict__ A, const unsigned short* __restrict__ B,
    float* __restrict__ Cf, unsigned short* __restrict__ Cb,
    int M, int N, int K, int lda, int ldb) {
  __shared__ unsigned short As[128 * 64];
  __shared__ unsigned short Bs[128 * 64];
  const int tid = threadIdx.x;
  const int wv = tid >> 6, l = tid & 63;
  const int wm0 = (wv >> 1) * 64, wn0 = (wv & 1) * 64;
  const int nid = xcd_remap(blockIdx.y * gridDim.x + blockIdx.x,
                            gridDim.x * gridDim.y);
  const int m0 = (nid / gridDim.x) * 128, n0 = (nid % gridDim.x) * 128;
  const int lrow = l & 15, lg = l >> 4;
  const int srow = l >> 3;
  const int scol = ((l & 7) ^ srow) * 8;
  const unsigned short* Ag = A + (size_t)(m0 + wv * 32 + srow) * lda + scol;
  const unsigned short* Bg = B + (size_t)(n0 + wv * 32 + srow) * ldb + scol;
  unsigned short* Al = As + (wv * 32) * 64;
  unsigned short* Bl = Bs + (wv * 32) * 64;

  f32x4 acc[4][4] = {};
  for (int k0 = 0; k0 < K; k0 += 64) {
    __syncthreads();
#pragma unroll
    for (int c = 0; c < 4; ++c) {
      gl2lds16(Ag + (size_t)(c * 8) * lda + k0, Al + c * 8 * 64);
      gl2lds16(Bg + (size_t)(c * 8) * ldb + k0, Bl + c * 8 * 64);
    }
    __syncthreads();
#pragma unroll
    for (int ks = 0; ks < 2; ++ks) {
      const int cidx = ((ks << 5) | (lg << 3)) ^ ((lrow & 7) << 3);
      short8 af[4], bfr[4];
#pragma unroll
      for (int i = 0; i < 4; ++i)
        af[i] = *reinterpret_cast<const short8*>(
            &As[(wm0 + i * 16 + lrow) * 64 + cidx]);
#pragma unroll
      for (int j = 0; j < 4; ++j)
        bfr[j] = *reinterpret_cast<const short8*>(
            &Bs[(wn0 + j * 16 + lrow) * 64 + cidx]);
#pragma unroll
      for (int i = 0; i < 4; ++i)
#pragma unroll
        for (int j = 0; j < 4; ++j)
          acc[i][j] = __builtin_amdgcn_mfma_f32_16x16x32_bf16(
              af[i], bfr[j], acc[i][j], 0, 0, 0);
    }
  }
#pragma unroll
  for (int i = 0; i < 4; ++i) {
#pragma unroll
    for (int r = 0; r < 4; ++r) {
      int m = m0 + wm0 + i * 16 + (l >> 4) * 4 + r;
      if (m < M) {
        size_t ro = (size_t)m * N;
#pragma unroll
        for (int j = 0; j < 4; ++j) {
          int n = n0 + wn0 + j * 16 + lrow;
          float v = acc[i][j][r];
          if (OP == OP_GELU) v = gelu_f(v);
          if (OP == OP_ADDTO) v += Cf[ro + n];
          if (WF32) Cf[ro + n] = v;
          if (WBF16) Cb[ro + n] = f2bf(v);
        }
      }
    }
  }
}

// ------- fused QKV GEMM (BK=64 swizzled): A[M,512] x Wqkv[768,512]^T -------
// Q pre-scaled by 0.125*log2(e) so attention softmax runs in exp2 domain.
__global__ __launch_bounds__(256) void bgemm_qkv_kernel(
    const unsigned short* __restrict__ A, const unsigned short* __restrict__ B,
    unsigned short* __restrict__ Q, unsigned short* __restrict__ Kq,
    unsigned short* __restrict__ Vq, int M) {
  __shared__ unsigned short As[128 * 64];
  __shared__ unsigned short Bs[128 * 64];
  const int tid = threadIdx.x;
  const int wv = tid >> 6, l = tid & 63;
  const int wm0 = (wv >> 1) * 64, wn0 = (wv & 1) * 64;
  const int nid = xcd_remap(blockIdx.y * gridDim.x + blockIdx.x,
                            gridDim.x * gridDim.y);
  const int m0 = (nid / gridDim.x) * 128;
  const int bx = nid % gridDim.x;
  const int n0 = bx * 128;
  const int lrow = l & 15, lg = l >> 4;
  const int srow = l >> 3;
  const int scol = ((l & 7) ^ srow) * 8;
  const unsigned short* Ag = A + (size_t)(m0 + wv * 32 + srow) * 512 + scol;
  const unsigned short* Bg = B + (size_t)(n0 + wv * 32 + srow) * 512 + scol;
  unsigned short* Al = As + (wv * 32) * 64;
  unsigned short* Bl = Bs + (wv * 32) * 64;

  f32x4 acc[4][4] = {};
  for (int k0 = 0; k0 < 512; k0 += 64) {
    __syncthreads();
#pragma unroll
    for (int c = 0; c < 4; ++c) {
      gl2lds16(Ag + (size_t)(c * 8) * 512 + k0, Al + c * 8 * 64);
      gl2lds16(Bg + (size_t)(c * 8) * 512 + k0, Bl + c * 8 * 64);
    }
    __syncthreads();
#pragma unroll
    for (int ks = 0; ks < 2; ++ks) {
      const int cidx = ((ks << 5) | (lg << 3)) ^ ((lrow & 7) << 3);
      short8 af[4], bfr[4];
#pragma unroll
      for (int i = 0; i < 4; ++i)
        af[i] = *reinterpret_cast<const short8*>(
            &As[(wm0 + i * 16 + lrow) * 64 + cidx]);
#pragma unroll
      for (int j = 0; j < 4; ++j)
        bfr[j] = *reinterpret_cast<const short8*>(
            &Bs[(wn0 + j * 16 + lrow) * 64 + cidx]);
#pragma unroll
      for (int i = 0; i < 4; ++i)
#pragma unroll
        for (int j = 0; j < 4; ++j)
          acc[i][j] = __builtin_amdgcn_mfma_f32_16x16x32_bf16(
              af[i], bfr[j], acc[i][j], 0, 0, 0);
    }
  }
  unsigned short* Co;
  int ldc, cbase;
  float scl;
  if (bx < 4)      { Co = Q;  ldc = 512; cbase = bx * 128; scl = 0.1803368801f; }
  else if (bx == 4){ Co = Kq; ldc = 128; cbase = 0;        scl = 1.0f;   }
  else             { Co = Vq; ldc = 128; cbase = 0;        scl = 1.0f;   }
#pragma unroll
  for (int i = 0; i < 4; ++i) {
#pragma unroll
    for (int r = 0; r < 4; ++r) {
      int m = m0 + wm0 + i * 16 + lg * 4 + r;
      if (m < M) {
#pragma unroll
        for (int j = 0; j < 4; ++j) {
          int n = cbase + wn0 + j * 16 + lrow;
          Co[(size_t)m * ldc + n] = f2bf(acc[i][j][r] * scl);
        }
      }
    }
  }
}

// ---- V transpose: [b*SL+t][128] -> Vt[(b*2+g)*64+d][544], chunk per block --
__global__ __launch_bounds__(256) void vtrans_kernel(
    const unsigned short* __restrict__ Vp, unsigned short* __restrict__ Vt) {
  const int g = blockIdx.x, b = blockIdx.y, t0 = blockIdx.z * 64;
  const int tid = threadIdx.x;
  __shared__ unsigned short T[64][72];
  const int tr = tid >> 2, c4 = (tid & 3) * 16;
  const int d = tid >> 2, tc = (tid & 3) * 16;
  int t = t0 + tr;
  ushort8v v0 = {}, v1 = {};
  if (t < SL) {
    const unsigned short* src = Vp + ((size_t)b * SL + t) * 128 + g * 64 + c4;
    v0 = *reinterpret_cast<const ushort8v*>(src);
    v1 = *reinterpret_cast<const ushort8v*>(src + 8);
  }
  *reinterpret_cast<ushort8v*>(&T[tr][c4]) = v0;
  *reinterpret_cast<ushort8v*>(&T[tr][c4 + 8]) = v1;
  __syncthreads();
  if (t0 + tc < 544) {
    unsigned short tmp[16];
#pragma unroll
    for (int i = 0; i < 16; ++i) tmp[i] = T[tc + i][d];
    unsigned short* dst = Vt + ((size_t)((b * 2 + g) * 64) + d) * 544 + t0 + tc;
    *reinterpret_cast<ushort8v*>(dst) = *reinterpret_cast<ushort8v*>(tmp);
    *reinterpret_cast<ushort8v*>(dst + 8) = *reinterpret_cast<ushort8v*>(tmp + 8);
  }
}

// --- MFMA flash attention: block (qt64, g, b) with XCD-locality remap,
// --- 4 waves (wave=head), exp2 softmax + defer-max, VGPR 84 (6 waves/SIMD).
__global__ __launch_bounds__(256, 2) void attn_mfma_kernel(
    const unsigned short* __restrict__ Qb, const unsigned short* __restrict__ Kb,
    const unsigned short* __restrict__ Vt, unsigned short* __restrict__ Ab) {
  const int lin = (blockIdx.z * gridDim.y + blockIdx.y) * gridDim.x + blockIdx.x;
  const int nid = xcd_remap(lin, 9 * 2 * NB);
  const int qt = nid % 9, g = (nid / 9) & 1, b = nid / 18;
  const int tid = threadIdx.x;
  const int w = tid >> 6, l = tid & 63;
  const int l15 = l & 15, lg = l >> 4;
  const int h = g * 4 + w;
  const int s0 = qt * 64;

  __shared__ unsigned short Plds[4][64][40];  // per-wave slice, stride 40

  short8 qf[4][2];
#pragma unroll
  for (int sf = 0; sf < 4; ++sf)
#pragma unroll
    for (int ks = 0; ks < 2; ++ks)
      qf[sf][ks] = *reinterpret_cast<const short8*>(
          Qb + ((size_t)b * SL + s0 + sf * 16 + l15) * 512 + h * 64 + ks * 32 + lg * 8);

  f32x4 Oacc[4][4] = {};
  float mrun[4] = {-1e30f, -1e30f, -1e30f, -1e30f};
  float lrun[4] = {0.f, 0.f, 0.f, 0.f};

  const size_t krow0 = (size_t)b * SL;
  const size_t vrow0 = (size_t)((b * 2 + g) * 64);

  for (int t0 = 0; t0 < 544; t0 += 32) {
    short8 kf[2][2];
#pragma unroll
    for (int tf = 0; tf < 2; ++tf)
#pragma unroll
      for (int ks = 0; ks < 2; ++ks)
        kf[tf][ks] = *reinterpret_cast<const short8*>(
            Kb + (krow0 + t0 + tf * 16 + l15) * 128 + g * 64 + ks * 32 + lg * 8);

    f32x4 Sacc[2][4] = {};
    __builtin_amdgcn_s_setprio(1);
#pragma unroll
    for (int tf = 0; tf < 2; ++tf)
#pragma unroll
      for (int sf = 0; sf < 4; ++sf) {
        Sacc[tf][sf] = __builtin_amdgcn_mfma_f32_16x16x32_bf16(
            kf[tf][0], qf[sf][0], Sacc[tf][sf], 0, 0, 0);
        Sacc[tf][sf] = __builtin_amdgcn_mfma_f32_16x16x32_bf16(
            kf[tf][1], qf[sf][1], Sacc[tf][sf], 0, 0, 0);
      }
    __builtin_amdgcn_s_setprio(0);

    if (t0 + 32 > SL) {  // mask t >= SL
#pragma unroll
      for (int tf = 0; tf < 2; ++tf)
#pragma unroll
        for (int sf = 0; sf < 4; ++sf)
#pragma unroll
          for (int r = 0; r < 4; ++r) {
            int t = t0 + tf * 16 + lg * 4 + r;
            Sacc[tf][sf][r] = (t < SL) ? Sacc[tf][sf][r] : -1e30f;
          }
    }

#pragma unroll
    for (int sf = 0; sf < 4; ++sf) {
      float pm = Sacc[0][sf][0];
#pragma unroll
      for (int r = 1; r < 4; ++r) pm = fmaxf(pm, Sacc[0][sf][r]);
#pragma unroll
      for (int r = 0; r < 4; ++r) pm = fmaxf(pm, Sacc[1][sf][r]);
      // defer-max (exp2 domain): rescale only when a row max grew past mrun+8
      if (!__all(pm <= mrun[sf] + 8.0f)) {
        float pmx = fmaxf(pm, __shfl_xor(pm, 16));
        pmx = fmaxf(pmx, __shfl_xor(pmx, 32));
        float mnew = fmaxf(mrun[sf], pmx);
        float rsc = exp2f(mrun[sf] - mnew);
        mrun[sf] = mnew;
        lrun[sf] *= rsc;
#pragma unroll
        for (int r = 0; r < 4; ++r) {
          float f = __shfl(rsc, lg * 4 + r);
#pragma unroll
          for (int df = 0; df < 4; ++df) Oacc[sf][df][r] *= f;
        }
      }
      const float mcur = mrun[sf];
      float ps = 0.f;
      float p[2][4];
#pragma unroll
      for (int tf = 0; tf < 2; ++tf)
#pragma unroll
        for (int r = 0; r < 4; ++r) {
          float e = exp2f(Sacc[tf][sf][r] - mcur);
          p[tf][r] = e;
          ps += e;
        }
      ps += __shfl_xor(ps, 16);
      ps += __shfl_xor(ps, 32);
      lrun[sf] += ps;
      const int srow = sf * 16 + l15;
#pragma unroll
      for (int tf = 0; tf < 2; ++tf) {
        unsigned pk0, pk1;
        asm("v_cvt_pk_bf16_f32 %0, %1, %2" : "=v"(pk0) : "v"(p[tf][0]), "v"(p[tf][1]));
        asm("v_cvt_pk_bf16_f32 %0, %1, %2" : "=v"(pk1) : "v"(p[tf][2]), "v"(p[tf][3]));
        unsigned* dst = reinterpret_cast<unsigned*>(&Plds[w][srow][tf * 16 + lg * 4]);
        dst[0] = pk0;
        dst[1] = pk1;
      }
    }

    short8 pa[4], vb[4];
#pragma unroll
    for (int mf = 0; mf < 4; ++mf)
      pa[mf] = *reinterpret_cast<const short8*>(&Plds[w][mf * 16 + l15][lg * 8]);
#pragma unroll
    for (int df = 0; df < 4; ++df)
      vb[df] = *reinterpret_cast<const short8*>(
          Vt + (vrow0 + df * 16 + l15) * 544 + t0 + lg * 8);
    __builtin_amdgcn_s_setprio(1);
#pragma unroll
    for (int mf = 0; mf < 4; ++mf)
#pragma unroll
      for (int df = 0; df < 4; ++df)
        Oacc[mf][df] = __builtin_amdgcn_mfma_f32_16x16x32_bf16(
            pa[mf], vb[df], Oacc[mf][df], 0, 0, 0);
    __builtin_amdgcn_s_setprio(0);
  }

#pragma unroll
  for (int sf = 0; sf < 4; ++sf) {
#pragma unroll
    for (int r = 0; r < 4; ++r) {
      float lr = __shfl(lrun[sf], lg * 4 + r);
      float inv = 1.0f / lr;
      int s = s0 + sf * 16 + lg * 4 + r;
      if (s < SL) {
        unsigned short* op = Ab + ((size_t)b * SL + s) * 512 + h * 64;
#pragma unroll
        for (int df = 0; df < 4; ++df)
          op[df * 16 + l15] = f2bf(Oacc[sf][df][r] * inv);
      }
    }
  }
}

// -------- attention pooling head: block per (h, b), KV = [M][1024] K|V ------
__global__ __launch_bounds__(256) void pool_kernel(
    const unsigned short* __restrict__ KV, const float* __restrict__ poolq,
    float* __restrict__ P) {
  const int h = blockIdx.x, b = blockIdx.y, tid = threadIdx.x;
  __shared__ float sc[SL];
  __shared__ float red[256];
  __shared__ float pqs[64];
  if (tid < 64) pqs[tid] = poolq[h * 64 + tid];
  __syncthreads();
  float tmax = -1e30f;
  for (int t = tid; t < SL; t += 256) {
    const ushort8v* kp = reinterpret_cast<const ushort8v*>(
        KV + ((size_t)(b * SL + t)) * 1024 + h * 64);
    float acc = 0.f;
#pragma unroll
    for (int c = 0; c < 8; ++c) {
      ushort8v v = kp[c];
#pragma unroll
      for (int j = 0; j < 8; ++j) acc += pqs[c * 8 + j] * bf2f(v[j]);
    }
    float s = acc * 0.125f;
    sc[t] = s;
    tmax = fmaxf(tmax, s);
  }
  red[tid] = tmax;
  __syncthreads();
  for (int off = 128; off >= 1; off >>= 1) {
    if (tid < off) red[tid] = fmaxf(red[tid], red[tid + off]);
    __syncthreads();
  }
  float mh = red[0];
  __syncthreads();
  float tsum = 0.f;
  for (int t = tid; t < SL; t += 256) {
    float e = __expf(sc[t] - mh);
    sc[t] = e;
    tsum += e;
  }
  red[tid] = tsum;
  __syncthreads();
  for (int off = 128; off >= 1; off >>= 1) {
    if (tid < off) red[tid] += red[tid + off];
    __syncthreads();
  }
  float inv = 1.0f / red[0];
  __syncthreads();
  const int d = tid & 63, tc = tid >> 6;
  float acc = 0.f;
  for (int t = tc; t < SL; t += 4)
    acc += sc[t] * bf2f(KV[((size_t)(b * SL + t)) * 1024 + 512 + h * 64 + d]);
  red[tid] = acc;
  __syncthreads();
  if (tid < 64) {
    float s = red[tid] + red[tid + 64] + red[tid + 128] + red[tid + 192];
    P[(size_t)b * 512 + h * 64 + tid] = s * inv;
  }
}

// ------------ split-K skinny GEMM (M=32): Cp[kc][32][N] partials ------------
__global__ __launch_bounds__(256) void skgemm_kernel(
    const float* __restrict__ A, const float* __restrict__ B,
    float* __restrict__ Cp, int N, int K) {
  const int n0 = blockIdx.x * 64, kc = blockIdx.y, k0 = kc * 64;
  const int tid = threadIdx.x;
  __shared__ float As[32][68];
  __shared__ float Rs[4][32][64];
  {
    int r = tid >> 3, c = (tid & 7) * 8;
    float4 v0 = *reinterpret_cast<const float4*>(A + (size_t)r * K + k0 + c);
    float4 v1 = *reinterpret_cast<const float4*>(A + (size_t)r * K + k0 + c + 4);
    *reinterpret_cast<float4*>(&As[r][c]) = v0;
    *reinterpret_cast<float4*>(&As[r][c + 4]) = v1;
  }
  __syncthreads();
  const int n = tid & 63, ks = tid >> 6;
  const float* Brow = B + (size_t)(n0 + n) * K + k0 + ks * 16;
  float bv[16];
#pragma unroll
  for (int kk = 0; kk < 16; ++kk) bv[kk] = Brow[kk];
  float acc[32];
#pragma unroll
  for (int m = 0; m < 32; ++m) acc[m] = 0.f;
#pragma unroll
  for (int kk = 0; kk < 16; ++kk) {
#pragma unroll
    for (int m = 0; m < 32; ++m) acc[m] += As[m][ks * 16 + kk] * bv[kk];
  }
#pragma unroll
  for (int m = 0; m < 32; ++m) Rs[ks][m][n] = acc[m];
  __syncthreads();
  for (int idx = tid; idx < 2048; idx += 256) {
    int m = idx >> 6, nn = idx & 63;
    float s = Rs[0][m][nn] + Rs[1][m][nn] + Rs[2][m][nn] + Rs[3][m][nn];
    Cp[((size_t)kc * 32 + m) * N + n0 + nn] = s;
  }
}

// ------------ split-K reduce + epilogue: C[32][N] (+)= op(sum_kc Cp) --------
template <int OP>
__global__ __launch_bounds__(256) void sred_kernel(
    const float* __restrict__ Cp, float* __restrict__ C, int N, int KC) {
  int idx = blockIdx.x * 256 + threadIdx.x;
  if (idx >= 32 * N) return;
  float s = 0.f;
  for (int k = 0; k < KC; ++k) s += Cp[(size_t)k * 32 * N + idx];
  if (OP == OP_GELU) s = gelu_f(s);
  if (OP == OP_ADDTO) s += C[idx];
  C[idx] = s;
}

// ---------------- layernorm over 512, one block per b ----------------
__global__ __launch_bounds__(256) void ln_kernel(float* __restrict__ Xg) {
  const int b = blockIdx.x, tid = threadIdx.x;
  __shared__ float red[256];
  float* x = Xg + (size_t)b * 512;
  float v0 = x[tid], v1 = x[tid + 256];
  red[tid] = v0 + v1;
  __syncthreads();
  for (int off = 128; off >= 1; off >>= 1) {
    if (tid < off) red[tid] += red[tid + off];
    __syncthreads();
  }
  float mu = red[0] * (1.0f / 512.0f);
  __syncthreads();
  float d0 = v0 - mu, d1 = v1 - mu;
  red[tid] = d0 * d0 + d1 * d1;
  __syncthreads();
  for (int off = 128; off >= 1; off >>= 1) {
    if (tid < off) red[tid] += red[tid + off];
    __syncthreads();
  }
  float var = red[0] * (1.0f / 512.0f);
  float inv = 1.0f / sqrtf(var + 1e-5f);
  x[tid] = d0 * inv;
  x[tid + 256] = d1 * inv;
}

extern "C" void kernel_launch(void* const* d_in, const int* in_sizes, int n_in,
                              void* d_out, int out_size, void* d_ws,
                              size_t ws_size, hipStream_t stream) {
  const void*  mask_raw = d_in[0];
  const int*   rpx  = (const int*)d_in[1];
  const int*   rpy  = (const int*)d_in[2];
  const int*   hx   = (const int*)d_in[3];
  const int*   hy   = (const int*)d_in[4];
  const float* steps = (const float*)d_in[5];
  const float* temp  = (const float*)d_in[6];
  const float* mc    = (const float*)d_in[7];
  const float* gw    = (const float*)d_in[8];
  const float* gb    = (const float*)d_in[9];
  const float* pex   = (const float*)d_in[10];
  const float* pey   = (const float*)d_in[11];
  const float* remb  = (const float*)d_in[12];
  const float* uemb  = (const float*)d_in[13];
  const float* qw    = (const float*)d_in[14];
  const float* kw    = (const float*)d_in[15];
  const float* vw    = (const float*)d_in[16];
  const float* pw    = (const float*)d_in[17];
  const float* f1    = (const float*)d_in[18];
  const float* f2    = (const float*)d_in[19];
  const float* pq    = (const float*)d_in[20];
  const float* pkw   = (const float*)d_in[21];
  const float* pvw   = (const float*)d_in[22];
  const float* ppw   = (const float*)d_in[23];
  const float* g1    = (const float*)d_in[24];
  const float* g2    = (const float*)d_in[25];
  const float* ow1   = (const float*)d_in[26];
  const float* ow2   = (const float*)d_in[27];
  float* out = (float*)d_out;
  char*  wsb = (char*)d_ws;

  // byte-offset workspace layout (~127.9 MB), padded rows: 16544
  float*          X   = (float*)(wsb + 0);                   // 16544x512 f32
  unsigned short* Xb  = (unsigned short*)(wsb + 33882112);   // 16544x512 bf16
  unsigned short* QbH = (unsigned short*)(wsb + 50823168);   // Q / FF-hidden-half base
  unsigned short* Kbb = (unsigned short*)(wsb + 67764224);   // K proj (dead during FF)
  unsigned short* VtB = (unsigned short*)(wsb + 71999488);   // Vt (dead during FF)
  unsigned short* Abb = (unsigned short*)(wsb + 76455936);   // V / attn out (dead during FF)
  unsigned short* Wb  = (unsigned short*)(wsb + 93396992);   // bf16 weights
  float*          Pb  = (float*)(wsb + 127475712);
  float*          Xg  = (float*)(wsb + 127541248);
  float*          Gh  = (float*)(wsb + 127606784);
  int*            mint  = (int*)(wsb + 127868928);
  int*            mflag = (int*)(wsb + 127934464);
  float*          Cp  = (float*)QbH;          // split-K partials (after pool)
  unsigned short* Hb  = QbH;                  // FF hidden half / pool-KV: 16544x1024 bf16

  // bf16 weight offsets (ushort elements)
  unsigned short* wqkv = Wb;                  // [6][768][512] fused q;k;v
  unsigned short* wpw  = Wb + 2359296;        // [pw;f1;f2;pkw;pvw] contiguous
  unsigned short* wf1  = Wb + 3932160;
  unsigned short* wf2  = Wb + 10223616;
  unsigned short* wpkv = Wb + 16515072;       // [1024][512] = [pk;pv] (adjacent)

  detect_mask_kernel<<<1, 256, 0, stream>>>((const unsigned int*)mask_raw, mflag);
  convert_mask_kernel<<<64, 256, 0, stream>>>(mask_raw, mflag, mint);

  f2bf_qkv_kernel<<<2304, 256, 0, stream>>>(qw, kw, vw, wqkv);
  f2bfw_kernel<<<14336, 256, 0, stream>>>(pw, f1, f2, pkw, pvw, wpw);

  gemb_kernel<<<dim3(8, NB), 256, 0, stream>>>(mint, steps, temp, mc, gw, gb, X, Xb);
  buildx_kernel<<<dim3(RR, NB), 128, 0, stream>>>(mint, rpx, rpy, hx, hy, pex,
                                                  pey, remb, uemb, X, Xb);

  const int Mfull = NB * SL;  // 16416
  for (int l = 0; l < 6; ++l) {
    bgemm_qkv_kernel<<<dim3(6, 129), 256, 0, stream>>>(
        Xb, wqkv + (size_t)l * 393216, QbH, Kbb, Abb, Mfull);
    vtrans_kernel<<<dim3(2, NB, 9), 256, 0, stream>>>(Abb, VtB);
    attn_mfma_kernel<<<dim3(9, 2, NB), 256, 0, stream>>>(QbH, Kbb, VtB, Abb);
    bgemm_kernel<OP_ADDTO, true, true><<<dim3(4, 129), 256, 0, stream>>>(
        Abb, wpw + (size_t)l * 262144, X, Xb, Mfull, 512, 512, 512, 512);
    // FF split over hidden dim: two halves of 1024, full-M grids
    for (int hh = 0; hh < 2; ++hh) {
      bgemm_kernel<OP_GELU, false, true><<<dim3(8, 129), 256, 0, stream>>>(
          Xb, wf1 + (size_t)l * 1048576 + (size_t)hh * 1024 * 512, nullptr, Hb,
          Mfull, 1024, 512, 512, 512);
      if (hh == 0)
        bgemm_kernel<OP_ADDTO, true, false><<<dim3(4, 129), 256, 0, stream>>>(
            Hb, wf2 + (size_t)l * 1048576, X, nullptr,
            Mfull, 512, 1024, 1024, 2048);
      else
        bgemm_kernel<OP_ADDTO, true, true><<<dim3(4, 129), 256, 0, stream>>>(
            Hb, wf2 + (size_t)l * 1048576 + 1024, X, Xb,
            Mfull, 512, 1024, 1024, 2048);
    }
  }

  // pooling head: fused K|V projection into Hb [M][1024], then block-per-(h,b)
  bgemm_kernel<OP_NONE, false, true><<<dim3(8, 129), 256, 0, stream>>>(
      Xb, wpkv, nullptr, Hb, Mfull, 1024, 512, 512, 512);
  pool_kernel<<<dim3(8, NB), 256, 0, stream>>>(Hb, pq, Pb);

  // small head MLP stack via split-K skinny GEMMs (Cp reuses QbH region)
  skgemm_kernel<<<dim3(8, 8), 256, 0, stream>>>(Pb, ppw, Cp, 512, 512);
  sred_kernel<OP_NONE><<<64, 256, 0, stream>>>(Cp, Xg, 512, 8);
  ln_kernel<<<NB, 256, 0, stream>>>(Xg);
  for (int l = 0; l < 4; ++l) {
    skgemm_kernel<<<dim3(32, 8), 256, 0, stream>>>(
        Xg, g1 + (size_t)l * 2048 * 512, Cp, 2048, 512);
    sred_kernel<OP_GELU><<<256, 256, 0, stream>>>(Cp, Gh, 2048, 8);
    skgemm_kernel<<<dim3(8, 32), 256, 0, stream>>>(
        Gh, g2 + (size_t)l * 512 * 2048, Cp, 512, 2048);
    sred_kernel<OP_ADDTO><<<64, 256, 0, stream>>>(Cp, Xg, 512, 32);
  }
  skgemm_kernel<<<dim3(32, 8), 256, 0, stream>>>(Xg, ow1, Cp, 2048, 512);
  sred_kernel<OP_GELU><<<256, 256, 0, stream>>>(Cp, Gh, 2048, 8);
  skgemm_kernel<<<dim3(16, 32), 256, 0, stream>>>(Gh, ow2, Cp, 1024, 2048);
  sred_kernel<OP_NONE><<<128, 256, 0, stream>>>(Cp, out, 1024, 32);
}

// Round 15
// 1774.877 us; speedup vs baseline: 1.2190x; 1.0056x over previous
//
#include <hip/hip_runtime.h>
#include <hip/hip_bf16.h>
#include <cstddef>
#include <cstdint>

// Problem dims
#define NB 32
#define RR 512
#define SL 513
#define EE 512

typedef short short8 __attribute__((ext_vector_type(8)));
typedef unsigned short ushort8v __attribute__((ext_vector_type(8)));
typedef unsigned short ushort4v __attribute__((ext_vector_type(4)));
typedef float f32x4 __attribute__((ext_vector_type(4)));

constexpr int OP_NONE = 0, OP_GELU = 1, OP_ADDTO = 2;

__device__ __forceinline__ float gelu_f(float x) {
  return 0.5f * x * (1.0f + erff(x * 0.7071067811865475f));
}
__device__ __forceinline__ float bf2f(unsigned short u) {
  return __uint_as_float(((unsigned)u) << 16);
}
__device__ __forceinline__ unsigned short f2bf(float f) {
  unsigned u = __float_as_uint(f);
  u += 0x7FFFu + ((u >> 16) & 1u);
  return (unsigned short)(u >> 16);
}
// async global->LDS, 16B per lane; lds must be wave-uniform base (lane*16 added by HW)
__device__ __forceinline__ void gl2lds16(const unsigned short* g, unsigned short* l) {
  __builtin_amdgcn_global_load_lds(
      (const __attribute__((address_space(1))) unsigned int*)(const void*)g,
      (__attribute__((address_space(3))) unsigned int*)(void*)l, 16, 0, 0);
}
// bijective XCD-chunked block-id remap (m204): consecutive nid -> same XCD
__device__ __forceinline__ int xcd_remap(int bid, int nwg) {
  int q = nwg >> 3, r = nwg & 7;
  int xcd = bid & 7, off = bid >> 3;
  return (xcd < r ? xcd * (q + 1) : r * (q + 1) + (xcd - r) * q) + off;
}

// ---------------- mask dtype detection (bool ambiguity hedge) ----------------
__global__ void detect_mask_kernel(const unsigned int* __restrict__ mask,
                                   int* __restrict__ flag) {
  __shared__ int notint, notfloat;
  if (threadIdx.x == 0) { notint = 0; notfloat = 0; }
  __syncthreads();
  for (int i = threadIdx.x; i < 4096; i += 256) {
    unsigned int v = mask[i];
    if (v > 1u) notint = 1;
    if (v != 0u && v != 0x3F800000u) notfloat = 1;
  }
  __syncthreads();
  if (threadIdx.x == 0) {
    int f = 2;
    if (!notint) f = 0;
    else if (!notfloat) f = 1;
    *flag = f;
  }
}

__global__ void convert_mask_kernel(const void* __restrict__ mask,
                                    const int* __restrict__ flag,
                                    int* __restrict__ mout) {
  int i = blockIdx.x * 256 + threadIdx.x;
  if (i >= NB * RR) return;
  int f = *flag;
  int v;
  if (f == 0)      v = (((const int*)mask)[i] != 0);
  else if (f == 1) v = (((const unsigned int*)mask)[i] != 0u);
  else             v = (((const unsigned char*)mask)[i] != 0);
  mout[i] = v;
}

// ---- batched weight convert: 5 segments [pw;f1;f2;pkw;pvw] -> contiguous ----
__global__ __launch_bounds__(256) void f2bfw_kernel(
    const float* __restrict__ pw, const float* __restrict__ f1,
    const float* __restrict__ f2, const float* __restrict__ pkw,
    const float* __restrict__ pvw, unsigned short* __restrict__ dst) {
  int i = (blockIdx.x * 256 + threadIdx.x) * 4;
  if (i >= 14680064) return;
  const float* src;
  if (i < 1572864)        src = pw  + i;
  else if (i < 7864320)   src = f1  + (i - 1572864);
  else if (i < 14155776)  src = f2  + (i - 7864320);
  else if (i < 14417920)  src = pkw + (i - 14155776);
  else                    src = pvw + (i - 14417920);
  float4 v = *reinterpret_cast<const float4*>(src);
  dst[i] = f2bf(v.x); dst[i + 1] = f2bf(v.y);
  dst[i + 2] = f2bf(v.z); dst[i + 3] = f2bf(v.w);
}

// ---- fused QKV weight concat+convert: dst[l][768][512], rows = [q;k;v] ----
__global__ __launch_bounds__(256) void f2bf_qkv_kernel(
    const float* __restrict__ qw, const float* __restrict__ kw,
    const float* __restrict__ vw, unsigned short* __restrict__ dst) {
  int idx = (blockIdx.x * 256 + threadIdx.x) * 4;
  if (idx >= 6 * 768 * 512) return;
  int l = idx / (768 * 512);
  int rem = idx - l * 768 * 512;
  int row = rem >> 9, col = rem & 511;
  const float* src;
  if (row < 512)      src = qw + ((size_t)l * 512 + row) * 512 + col;
  else if (row < 640) src = kw + ((size_t)l * 128 + (row - 512)) * 512 + col;
  else                src = vw + ((size_t)l * 128 + (row - 640)) * 512 + col;
  float4 v = *reinterpret_cast<const float4*>(src);
  dst[idx] = f2bf(v.x); dst[idx + 1] = f2bf(v.y);
  dst[idx + 2] = f2bf(v.z); dst[idx + 3] = f2bf(v.w);
}

// ---------------- global-feature embedding: X[b,0,:] (+ bf16 shadow) -------
__global__ __launch_bounds__(256) void gemb_kernel(
    const int* __restrict__ mask, const float* __restrict__ steps,
    const float* __restrict__ temp, const float* __restrict__ mc,
    const float* __restrict__ gw, const float* __restrict__ gb,
    float* __restrict__ X, unsigned short* __restrict__ Xb) {
  const int b = blockIdx.y, e0 = blockIdx.x * 64;
  const int tid = threadIdx.x;
  __shared__ float gd[516];
  gd[tid]       = (float)mask[b * RR + tid];
  gd[tid + 256] = (float)mask[b * RR + tid + 256];
  if (tid == 0) {
    gd[512] = steps[b] * (1.0f / 512.0f);
    gd[513] = logf(temp[b]);
    gd[514] = mc[b];
  }
  __syncthreads();
  const int e = e0 + (tid >> 2), q = tid & 3;
  const float* w = gw + (size_t)e * 515;
  const int j0 = q * 129;
  const int j1 = (j0 + 129 < 515) ? j0 + 129 : 515;
  float acc = 0.f;
  for (int j = j0; j < j1; ++j) acc += gd[j] * w[j];
  acc += __shfl_xor(acc, 1);
  acc += __shfl_xor(acc, 2);
  if (q == 0) {
    float v = acc + gb[e];
    X[(size_t)b * SL * EE + e] = v;
    Xb[(size_t)b * SL * EE + e] = f2bf(v);
  }
}

// ---------------- room rows: X[b,1+r,:] (+ bf16 shadow) ----------------
__global__ __launch_bounds__(128) void buildx_kernel(
    const int* __restrict__ mask, const int* __restrict__ rpx,
    const int* __restrict__ rpy, const int* __restrict__ hx,
    const int* __restrict__ hy, const float* __restrict__ pex,
    const float* __restrict__ pey, const float* __restrict__ remb,
    const float* __restrict__ uemb, float* __restrict__ X,
    unsigned short* __restrict__ Xb) {
  const int r = blockIdx.x, b = blockIdx.y;
  const int e = threadIdx.x * 4;
  float4 v;
  if (mask[b * RR + r]) {
    int ix = rpx[b * RR + r] + hx[r];
    int iy = rpy[b * RR + r] + hy[r];
    float4 a = *reinterpret_cast<const float4*>(pex + (size_t)ix * EE + e);
    float4 c = *reinterpret_cast<const float4*>(pey + (size_t)iy * EE + e);
    float4 d = *reinterpret_cast<const float4*>(remb + (size_t)r * EE + e);
    v = make_float4(a.x + c.x + d.x, a.y + c.y + d.y, a.z + c.z + d.z,
                    a.w + c.w + d.w);
  } else {
    v = *reinterpret_cast<const float4*>(uemb + (size_t)r * EE + e);
  }
  size_t off = ((size_t)b * SL + r + 1) * EE + e;
  *reinterpret_cast<float4*>(X + off) = v;
  ushort4v bv = {f2bf(v.x), f2bf(v.y), f2bf(v.z), f2bf(v.w)};
  *reinterpret_cast<ushort4v*>(Xb + off) = bv;
}

// ---- bf16 MFMA GEMM: BK=64, T2 XOR-swizzle + bijective XCD block remap ----
template <int OP, bool WF32, bool WBF16>
__global__ __launch_bounds__(256) void bgemm_kernel(
    const unsigned short* __restrict__ A, const unsigned short* __restrict__ B,
    float* __restrict__ Cf, unsigned short* __restrict__ Cb,
    int M, int N, int K, int lda, int ldb) {
  __shared__ unsigned short As[128 * 64];
  __shared__ unsigned short Bs[128 * 64];
  const int tid = threadIdx.x;
  const int wv = tid >> 6, l = tid & 63;
  const int wm0 = (wv >> 1) * 64, wn0 = (wv & 1) * 64;
  const int nid = xcd_remap(blockIdx.y * gridDim.x + blockIdx.x,
                            gridDim.x * gridDim.y);
  const int m0 = (nid / gridDim.x) * 128, n0 = (nid % gridDim.x) * 128;
  const int lrow = l & 15, lg = l >> 4;
  const int srow = l >> 3;
  const int scol = ((l & 7) ^ srow) * 8;
  const unsigned short* Ag = A + (size_t)(m0 + wv * 32 + srow) * lda + scol;
  const unsigned short* Bg = B + (size_t)(n0 + wv * 32 + srow) * ldb + scol;
  unsigned short* Al = As + (wv * 32) * 64;
  unsigned short* Bl = Bs + (wv * 32) * 64;

  f32x4 acc[4][4] = {};
  for (int k0 = 0; k0 < K; k0 += 64) {
    __syncthreads();
#pragma unroll
    for (int c = 0; c < 4; ++c) {
      gl2lds16(Ag + (size_t)(c * 8) * lda + k0, Al + c * 8 * 64);
      gl2lds16(Bg + (size_t)(c * 8) * ldb + k0, Bl + c * 8 * 64);
    }
    __syncthreads();
#pragma unroll
    for (int ks = 0; ks < 2; ++ks) {
      const int cidx = ((ks << 5) | (lg << 3)) ^ ((lrow & 7) << 3);
      short8 af[4], bfr[4];
#pragma unroll
      for (int i = 0; i < 4; ++i)
        af[i] = *reinterpret_cast<const short8*>(
            &As[(wm0 + i * 16 + lrow) * 64 + cidx]);
#pragma unroll
      for (int j = 0; j < 4; ++j)
        bfr[j] = *reinterpret_cast<const short8*>(
            &Bs[(wn0 + j * 16 + lrow) * 64 + cidx]);
#pragma unroll
      for (int i = 0; i < 4; ++i)
#pragma unroll
        for (int j = 0; j < 4; ++j)
          acc[i][j] = __builtin_amdgcn_mfma_f32_16x16x32_bf16(
              af[i], bfr[j], acc[i][j], 0, 0, 0);
    }
  }
#pragma unroll
  for (int i = 0; i < 4; ++i) {
#pragma unroll
    for (int r = 0; r < 4; ++r) {
      int m = m0 + wm0 + i * 16 + (l >> 4) * 4 + r;
      if (m < M) {
        size_t ro = (size_t)m * N;
#pragma unroll
        for (int j = 0; j < 4; ++j) {
          int n = n0 + wn0 + j * 16 + lrow;
          float v = acc[i][j][r];
          if (OP == OP_GELU) v = gelu_f(v);
          if (OP == OP_ADDTO) v += Cf[ro + n];
          if (WF32) Cf[ro + n] = v;
          if (WBF16) Cb[ro + n] = f2bf(v);
        }
      }
    }
  }
}

// ------- fused QKV GEMM (BK=64 swizzled): A[M,512] x Wqkv[768,512]^T -------
// Q pre-scaled by 0.125*log2(e) so attention softmax runs in exp2 domain.
__global__ __launch_bounds__(256) void bgemm_qkv_kernel(
    const unsigned short* __restrict__ A, const unsigned short* __restrict__ B,
    unsigned short* __restrict__ Q, unsigned short* __restrict__ Kq,
    unsigned short* __restrict__ Vq, int M) {
  __shared__ unsigned short As[128 * 64];
  __shared__ unsigned short Bs[128 * 64];
  const int tid = threadIdx.x;
  const int wv = tid >> 6, l = tid & 63;
  const int wm0 = (wv >> 1) * 64, wn0 = (wv & 1) * 64;
  const int nid = xcd_remap(blockIdx.y * gridDim.x + blockIdx.x,
                            gridDim.x * gridDim.y);
  const int m0 = (nid / gridDim.x) * 128;
  const int bx = nid % gridDim.x;
  const int n0 = bx * 128;
  const int lrow = l & 15, lg = l >> 4;
  const int srow = l >> 3;
  const int scol = ((l & 7) ^ srow) * 8;
  const unsigned short* Ag = A + (size_t)(m0 + wv * 32 + srow) * 512 + scol;
  const unsigned short* Bg = B + (size_t)(n0 + wv * 32 + srow) * 512 + scol;
  unsigned short* Al = As + (wv * 32) * 64;
  unsigned short* Bl = Bs + (wv * 32) * 64;

  f32x4 acc[4][4] = {};
  for (int k0 = 0; k0 < 512; k0 += 64) {
    __syncthreads();
#pragma unroll
    for (int c = 0; c < 4; ++c) {
      gl2lds16(Ag + (size_t)(c * 8) * 512 + k0, Al + c * 8 * 64);
      gl2lds16(Bg + (size_t)(c * 8) * 512 + k0, Bl + c * 8 * 64);
    }
    __syncthreads();
#pragma unroll
    for (int ks = 0; ks < 2; ++ks) {
      const int cidx = ((ks << 5) | (lg << 3)) ^ ((lrow & 7) << 3);
      short8 af[4], bfr[4];
#pragma unroll
      for (int i = 0; i < 4; ++i)
        af[i] = *reinterpret_cast<const short8*>(
            &As[(wm0 + i * 16 + lrow) * 64 + cidx]);
#pragma unroll
      for (int j = 0; j < 4; ++j)
        bfr[j] = *reinterpret_cast<const short8*>(
            &Bs[(wn0 + j * 16 + lrow) * 64 + cidx]);
#pragma unroll
      for (int i = 0; i < 4; ++i)
#pragma unroll
        for (int j = 0; j < 4; ++j)
          acc[i][j] = __builtin_amdgcn_mfma_f32_16x16x32_bf16(
              af[i], bfr[j], acc[i][j], 0, 0, 0);
    }
  }
  unsigned short* Co;
  int ldc, cbase;
  float scl;
  if (bx < 4)      { Co = Q;  ldc = 512; cbase = bx * 128; scl = 0.1803368801f; }
  else if (bx == 4){ Co = Kq; ldc = 128; cbase = 0;        scl = 1.0f;   }
  else             { Co = Vq; ldc = 128; cbase = 0;        scl = 1.0f;   }
#pragma unroll
  for (int i = 0; i < 4; ++i) {
#pragma unroll
    for (int r = 0; r < 4; ++r) {
      int m = m0 + wm0 + i * 16 + lg * 4 + r;
      if (m < M) {
#pragma unroll
        for (int j = 0; j < 4; ++j) {
          int n = cbase + wn0 + j * 16 + lrow;
          Co[(size_t)m * ldc + n] = f2bf(acc[i][j][r] * scl);
        }
      }
    }
  }
}

// ---- V transpose: [b*SL+t][128] -> Vt[(b*2+g)*64+d][544], chunk per block --
__global__ __launch_bounds__(256) void vtrans_kernel(
    const unsigned short* __restrict__ Vp, unsigned short* __restrict__ Vt) {
  const int g = blockIdx.x, b = blockIdx.y, t0 = blockIdx.z * 64;
  const int tid = threadIdx.x;
  __shared__ unsigned short T[64][72];
  const int tr = tid >> 2, c4 = (tid & 3) * 16;
  const int d = tid >> 2, tc = (tid & 3) * 16;
  int t = t0 + tr;
  ushort8v v0 = {}, v1 = {};
  if (t < SL) {
    const unsigned short* src = Vp + ((size_t)b * SL + t) * 128 + g * 64 + c4;
    v0 = *reinterpret_cast<const ushort8v*>(src);
    v1 = *reinterpret_cast<const ushort8v*>(src + 8);
  }
  *reinterpret_cast<ushort8v*>(&T[tr][c4]) = v0;
  *reinterpret_cast<ushort8v*>(&T[tr][c4 + 8]) = v1;
  __syncthreads();
  if (t0 + tc < 544) {
    unsigned short tmp[16];
#pragma unroll
    for (int i = 0; i < 16; ++i) tmp[i] = T[tc + i][d];
    unsigned short* dst = Vt + ((size_t)((b * 2 + g) * 64) + d) * 544 + t0 + tc;
    *reinterpret_cast<ushort8v*>(dst) = *reinterpret_cast<ushort8v*>(tmp);
    *reinterpret_cast<ushort8v*>(dst + 8) = *reinterpret_cast<ushort8v*>(tmp + 8);
  }
}

// --- MFMA flash attention: block (qt64, g, b) with XCD-locality remap,
// --- 4 waves (wave=head), exp2 softmax + defer-max, VGPR 84 (6 waves/SIMD).
__global__ __launch_bounds__(256, 2) void attn_mfma_kernel(
    const unsigned short* __restrict__ Qb, const unsigned short* __restrict__ Kb,
    const unsigned short* __restrict__ Vt, unsigned short* __restrict__ Ab) {
  const int lin = (blockIdx.z * gridDim.y + blockIdx.y) * gridDim.x + blockIdx.x;
  const int nid = xcd_remap(lin, 9 * 2 * NB);
  const int qt = nid % 9, g = (nid / 9) & 1, b = nid / 18;
  const int tid = threadIdx.x;
  const int w = tid >> 6, l = tid & 63;
  const int l15 = l & 15, lg = l >> 4;
  const int h = g * 4 + w;
  const int s0 = qt * 64;

  __shared__ unsigned short Plds[4][64][40];  // per-wave slice, stride 40

  short8 qf[4][2];
#pragma unroll
  for (int sf = 0; sf < 4; ++sf)
#pragma unroll
    for (int ks = 0; ks < 2; ++ks)
      qf[sf][ks] = *reinterpret_cast<const short8*>(
          Qb + ((size_t)b * SL + s0 + sf * 16 + l15) * 512 + h * 64 + ks * 32 + lg * 8);

  f32x4 Oacc[4][4] = {};
  float mrun[4] = {-1e30f, -1e30f, -1e30f, -1e30f};
  float lrun[4] = {0.f, 0.f, 0.f, 0.f};

  const size_t krow0 = (size_t)b * SL;
  const size_t vrow0 = (size_t)((b * 2 + g) * 64);

  for (int t0 = 0; t0 < 544; t0 += 32) {
    short8 kf[2][2];
#pragma unroll
    for (int tf = 0; tf < 2; ++tf)
#pragma unroll
      for (int ks = 0; ks < 2; ++ks)
        kf[tf][ks] = *reinterpret_cast<const short8*>(
            Kb + (krow0 + t0 + tf * 16 + l15) * 128 + g * 64 + ks * 32 + lg * 8);

    f32x4 Sacc[2][4] = {};
    __builtin_amdgcn_s_setprio(1);
#pragma unroll
    for (int tf = 0; tf < 2; ++tf)
#pragma unroll
      for (int sf = 0; sf < 4; ++sf) {
        Sacc[tf][sf] = __builtin_amdgcn_mfma_f32_16x16x32_bf16(
            kf[tf][0], qf[sf][0], Sacc[tf][sf], 0, 0, 0);
        Sacc[tf][sf] = __builtin_amdgcn_mfma_f32_16x16x32_bf16(
            kf[tf][1], qf[sf][1], Sacc[tf][sf], 0, 0, 0);
      }
    __builtin_amdgcn_s_setprio(0);

    if (t0 + 32 > SL) {  // mask t >= SL
#pragma unroll
      for (int tf = 0; tf < 2; ++tf)
#pragma unroll
        for (int sf = 0; sf < 4; ++sf)
#pragma unroll
          for (int r = 0; r < 4; ++r) {
            int t = t0 + tf * 16 + lg * 4 + r;
            Sacc[tf][sf][r] = (t < SL) ? Sacc[tf][sf][r] : -1e30f;
          }
    }

#pragma unroll
    for (int sf = 0; sf < 4; ++sf) {
      float pm = Sacc[0][sf][0];
#pragma unroll
      for (int r = 1; r < 4; ++r) pm = fmaxf(pm, Sacc[0][sf][r]);
#pragma unroll
      for (int r = 0; r < 4; ++r) pm = fmaxf(pm, Sacc[1][sf][r]);
      // defer-max (exp2 domain): rescale only when a row max grew past mrun+8
      if (!__all(pm <= mrun[sf] + 8.0f)) {
        float pmx = fmaxf(pm, __shfl_xor(pm, 16));
        pmx = fmaxf(pmx, __shfl_xor(pmx, 32));
        float mnew = fmaxf(mrun[sf], pmx);
        float rsc = exp2f(mrun[sf] - mnew);
        mrun[sf] = mnew;
        lrun[sf] *= rsc;
#pragma unroll
        for (int r = 0; r < 4; ++r) {
          float f = __shfl(rsc, lg * 4 + r);
#pragma unroll
          for (int df = 0; df < 4; ++df) Oacc[sf][df][r] *= f;
        }
      }
      const float mcur = mrun[sf];
      float ps = 0.f;
      float p[2][4];
#pragma unroll
      for (int tf = 0; tf < 2; ++tf)
#pragma unroll
        for (int r = 0; r < 4; ++r) {
          float e = exp2f(Sacc[tf][sf][r] - mcur);
          p[tf][r] = e;
          ps += e;
        }
      ps += __shfl_xor(ps, 16);
      ps += __shfl_xor(ps, 32);
      lrun[sf] += ps;
      const int srow = sf * 16 + l15;
#pragma unroll
      for (int tf = 0; tf < 2; ++tf) {
        unsigned pk0, pk1;
        asm("v_cvt_pk_bf16_f32 %0, %1, %2" : "=v"(pk0) : "v"(p[tf][0]), "v"(p[tf][1]));
        asm("v_cvt_pk_bf16_f32 %0, %1, %2" : "=v"(pk1) : "v"(p[tf][2]), "v"(p[tf][3]));
        unsigned* dst = reinterpret_cast<unsigned*>(&Plds[w][srow][tf * 16 + lg * 4]);
        dst[0] = pk0;
        dst[1] = pk1;
      }
    }

    short8 pa[4], vb[4];
#pragma unroll
    for (int mf = 0; mf < 4; ++mf)
      pa[mf] = *reinterpret_cast<const short8*>(&Plds[w][mf * 16 + l15][lg * 8]);
#pragma unroll
    for (int df = 0; df < 4; ++df)
      vb[df] = *reinterpret_cast<const short8*>(
          Vt + (vrow0 + df * 16 + l15) * 544 + t0 + lg * 8);
    __builtin_amdgcn_s_setprio(1);
#pragma unroll
    for (int mf = 0; mf < 4; ++mf)
#pragma unroll
      for (int df = 0; df < 4; ++df)
        Oacc[mf][df] = __builtin_amdgcn_mfma_f32_16x16x32_bf16(
            pa[mf], vb[df], Oacc[mf][df], 0, 0, 0);
    __builtin_amdgcn_s_setprio(0);
  }

#pragma unroll
  for (int sf = 0; sf < 4; ++sf) {
#pragma unroll
    for (int r = 0; r < 4; ++r) {
      float lr = __shfl(lrun[sf], lg * 4 + r);
      float inv = 1.0f / lr;
      int s = s0 + sf * 16 + lg * 4 + r;
      if (s < SL) {
        unsigned short* op = Ab + ((size_t)b * SL + s) * 512 + h * 64;
#pragma unroll
        for (int df = 0; df < 4; ++df)
          op[df * 16 + l15] = f2bf(Oacc[sf][df][r] * inv);
      }
    }
  }
}

// -------- attention pooling head: block per (h, b), KV = [M][1024] K|V ------
__global__ __launch_bounds__(256) void pool_kernel(
    const unsigned short* __restrict__ KV, const float* __restrict__ poolq,
    float* __restrict__ P) {
  const int h = blockIdx.x, b = blockIdx.y, tid = threadIdx.x;
  __shared__ float sc[SL];
  __shared__ float red[256];
  __shared__ float pqs[64];
  if (tid < 64) pqs[tid] = poolq[h * 64 + tid];
  __syncthreads();
  float tmax = -1e30f;
  for (int t = tid; t < SL; t += 256) {
    const ushort8v* kp = reinterpret_cast<const ushort8v*>(
        KV + ((size_t)(b * SL + t)) * 1024 + h * 64);
    float acc = 0.f;
#pragma unroll
    for (int c = 0; c < 8; ++c) {
      ushort8v v = kp[c];
#pragma unroll
      for (int j = 0; j < 8; ++j) acc += pqs[c * 8 + j] * bf2f(v[j]);
    }
    float s = acc * 0.125f;
    sc[t] = s;
    tmax = fmaxf(tmax, s);
  }
  red[tid] = tmax;
  __syncthreads();
  for (int off = 128; off >= 1; off >>= 1) {
    if (tid < off) red[tid] = fmaxf(red[tid], red[tid + off]);
    __syncthreads();
  }
  float mh = red[0];
  __syncthreads();
  float tsum = 0.f;
  for (int t = tid; t < SL; t += 256) {
    float e = __expf(sc[t] - mh);
    sc[t] = e;
    tsum += e;
  }
  red[tid] = tsum;
  __syncthreads();
  for (int off = 128; off >= 1; off >>= 1) {
    if (tid < off) red[tid] += red[tid + off];
    __syncthreads();
  }
  float inv = 1.0f / red[0];
  __syncthreads();
  const int d = tid & 63, tc = tid >> 6;
  float acc = 0.f;
  for (int t = tc; t < SL; t += 4)
    acc += sc[t] * bf2f(KV[((size_t)(b * SL + t)) * 1024 + 512 + h * 64 + d]);
  red[tid] = acc;
  __syncthreads();
  if (tid < 64) {
    float s = red[tid] + red[tid + 64] + red[tid + 128] + red[tid + 192];
    P[(size_t)b * 512 + h * 64 + tid] = s * inv;
  }
}

// ---- split-K skinny GEMM (M=32): Cp[kc][32][N] partials. A may itself be
// ---- partials [AKC][32][K] summed on load (fixed order) + AOP epilogue.
template <int AOP, int AKC>
__global__ __launch_bounds__(256) void skgemm_kernel(
    const float* __restrict__ A, const float* __restrict__ B,
    float* __restrict__ Cp, int N, int K) {
  const int n0 = blockIdx.x * 64, kc = blockIdx.y, k0 = kc * 64;
  const int tid = threadIdx.x;
  __shared__ float As[32][68];
  __shared__ float Rs[4][32][64];
  {
    int r = tid >> 3, c = (tid & 7) * 8;
    float4 v0 = make_float4(0.f, 0.f, 0.f, 0.f);
    float4 v1 = make_float4(0.f, 0.f, 0.f, 0.f);
    if (AKC == 1) {
      v0 = *reinterpret_cast<const float4*>(A + (size_t)r * K + k0 + c);
      v1 = *reinterpret_cast<const float4*>(A + (size_t)r * K + k0 + c + 4);
    } else {
      for (int k = 0; k < AKC; ++k) {
        const float* src = A + ((size_t)k * 32 + r) * K + k0 + c;
        float4 a0 = *reinterpret_cast<const float4*>(src);
        float4 a1 = *reinterpret_cast<const float4*>(src + 4);
        v0.x += a0.x; v0.y += a0.y; v0.z += a0.z; v0.w += a0.w;
        v1.x += a1.x; v1.y += a1.y; v1.z += a1.z; v1.w += a1.w;
      }
      if (AOP == OP_GELU) {
        v0.x = gelu_f(v0.x); v0.y = gelu_f(v0.y);
        v0.z = gelu_f(v0.z); v0.w = gelu_f(v0.w);
        v1.x = gelu_f(v1.x); v1.y = gelu_f(v1.y);
        v1.z = gelu_f(v1.z); v1.w = gelu_f(v1.w);
      }
    }
    *reinterpret_cast<float4*>(&As[r][c]) = v0;
    *reinterpret_cast<float4*>(&As[r][c + 4]) = v1;
  }
  __syncthreads();
  const int n = tid & 63, ks = tid >> 6;
  const float* Brow = B + (size_t)(n0 + n) * K + k0 + ks * 16;
  float bv[16];
#pragma unroll
  for (int kk = 0; kk < 16; ++kk) bv[kk] = Brow[kk];
  float acc[32];
#pragma unroll
  for (int m = 0; m < 32; ++m) acc[m] = 0.f;
#pragma unroll
  for (int kk = 0; kk < 16; ++kk) {
#pragma unroll
    for (int m = 0; m < 32; ++m) acc[m] += As[m][ks * 16 + kk] * bv[kk];
  }
#pragma unroll
  for (int m = 0; m < 32; ++m) Rs[ks][m][n] = acc[m];
  __syncthreads();
  for (int idx = tid; idx < 2048; idx += 256) {
    int m = idx >> 6, nn = idx & 63;
    float s = Rs[0][m][nn] + Rs[1][m][nn] + Rs[2][m][nn] + Rs[3][m][nn];
    Cp[((size_t)kc * 32 + m) * N + n0 + nn] = s;
  }
}

// ------------ split-K reduce + epilogue: C[32][N] (+)= op(sum_kc Cp) --------
template <int OP>
__global__ __launch_bounds__(256) void sred_kernel(
    const float* __restrict__ Cp, float* __restrict__ C, int N, int KC) {
  int idx = blockIdx.x * 256 + threadIdx.x;
  if (idx >= 32 * N) return;
  float s = 0.f;
  for (int k = 0; k < KC; ++k) s += Cp[(size_t)k * 32 * N + idx];
  if (OP == OP_GELU) s = gelu_f(s);
  if (OP == OP_ADDTO) s += C[idx];
  C[idx] = s;
}

// ---- layernorm over 512 with fused KC=8 partial reduce: Xg = LN(sum Cp) ----
__global__ __launch_bounds__(256) void ln_kernel(
    const float* __restrict__ Cp, float* __restrict__ Xg) {
  const int b = blockIdx.x, tid = threadIdx.x;
  __shared__ float red[256];
  float v0 = 0.f, v1 = 0.f;
#pragma unroll
  for (int k = 0; k < 8; ++k) {
    const float* p = Cp + ((size_t)k * 32 + b) * 512;
    v0 += p[tid];
    v1 += p[tid + 256];
  }
  red[tid] = v0 + v1;
  __syncthreads();
  for (int off = 128; off >= 1; off >>= 1) {
    if (tid < off) red[tid] += red[tid + off];
    __syncthreads();
  }
  float mu = red[0] * (1.0f / 512.0f);
  __syncthreads();
  float d0 = v0 - mu, d1 = v1 - mu;
  red[tid] = d0 * d0 + d1 * d1;
  __syncthreads();
  for (int off = 128; off >= 1; off >>= 1) {
    if (tid < off) red[tid] += red[tid + off];
    __syncthreads();
  }
  float var = red[0] * (1.0f / 512.0f);
  float inv = 1.0f / sqrtf(var + 1e-5f);
  float* x = Xg + (size_t)b * 512;
  x[tid] = d0 * inv;
  x[tid + 256] = d1 * inv;
}

extern "C" void kernel_launch(void* const* d_in, const int* in_sizes, int n_in,
                              void* d_out, int out_size, void* d_ws,
                              size_t ws_size, hipStream_t stream) {
  const void*  mask_raw = d_in[0];
  const int*   rpx  = (const int*)d_in[1];
  const int*   rpy  = (const int*)d_in[2];
  const int*   hx   = (const int*)d_in[3];
  const int*   hy   = (const int*)d_in[4];
  const float* steps = (const float*)d_in[5];
  const float* temp  = (const float*)d_in[6];
  const float* mc    = (const float*)d_in[7];
  const float* gw    = (const float*)d_in[8];
  const float* gb    = (const float*)d_in[9];
  const float* pex   = (const float*)d_in[10];
  const float* pey   = (const float*)d_in[11];
  const float* remb  = (const float*)d_in[12];
  const float* uemb  = (const float*)d_in[13];
  const float* qw    = (const float*)d_in[14];
  const float* kw    = (const float*)d_in[15];
  const float* vw    = (const float*)d_in[16];
  const float* pw    = (const float*)d_in[17];
  const float* f1    = (const float*)d_in[18];
  const float* f2    = (const float*)d_in[19];
  const float* pq    = (const float*)d_in[20];
  const float* pkw   = (const float*)d_in[21];
  const float* pvw   = (const float*)d_in[22];
  const float* ppw   = (const float*)d_in[23];
  const float* g1    = (const float*)d_in[24];
  const float* g2    = (const float*)d_in[25];
  const float* ow1   = (const float*)d_in[26];
  const float* ow2   = (const float*)d_in[27];
  float* out = (float*)d_out;
  char*  wsb = (char*)d_ws;

  // byte-offset workspace layout (~127.9 MB), padded rows: 16544
  float*          X   = (float*)(wsb + 0);                   // 16544x512 f32
  unsigned short* Xb  = (unsigned short*)(wsb + 33882112);   // 16544x512 bf16
  unsigned short* QbH = (unsigned short*)(wsb + 50823168);   // Q / FF-hidden-half base
  unsigned short* Kbb = (unsigned short*)(wsb + 67764224);   // K proj (dead during FF)
  unsigned short* VtB = (unsigned short*)(wsb + 71999488);   // Vt (dead during FF)
  unsigned short* Abb = (unsigned short*)(wsb + 76455936);   // V / attn out (dead during FF)
  unsigned short* Wb  = (unsigned short*)(wsb + 93396992);   // bf16 weights
  float*          Pb  = (float*)(wsb + 127475712);
  float*          Xg  = (float*)(wsb + 127541248);
  int*            mint  = (int*)(wsb + 127868928);
  int*            mflag = (int*)(wsb + 127934464);
  float*          CpA = (float*)QbH;               // partials A (<=2 MB)
  float*          CpB = (float*)(wsb + 55017472);  // partials B (<=4 MB)
  unsigned short* Hb  = QbH;                       // FF hidden half / pool-KV

  // bf16 weight offsets (ushort elements)
  unsigned short* wqkv = Wb;                  // [6][768][512] fused q;k;v
  unsigned short* wpw  = Wb + 2359296;        // [pw;f1;f2;pkw;pvw] contiguous
  unsigned short* wf1  = Wb + 3932160;
  unsigned short* wf2  = Wb + 10223616;
  unsigned short* wpkv = Wb + 16515072;       // [1024][512] = [pk;pv] (adjacent)

  detect_mask_kernel<<<1, 256, 0, stream>>>((const unsigned int*)mask_raw, mflag);
  convert_mask_kernel<<<64, 256, 0, stream>>>(mask_raw, mflag, mint);

  f2bf_qkv_kernel<<<2304, 256, 0, stream>>>(qw, kw, vw, wqkv);
  f2bfw_kernel<<<14336, 256, 0, stream>>>(pw, f1, f2, pkw, pvw, wpw);

  gemb_kernel<<<dim3(8, NB), 256, 0, stream>>>(mint, steps, temp, mc, gw, gb, X, Xb);
  buildx_kernel<<<dim3(RR, NB), 128, 0, stream>>>(mint, rpx, rpy, hx, hy, pex,
                                                  pey, remb, uemb, X, Xb);

  const int Mfull = NB * SL;  // 16416
  for (int l = 0; l < 6; ++l) {
    bgemm_qkv_kernel<<<dim3(6, 129), 256, 0, stream>>>(
        Xb, wqkv + (size_t)l * 393216, QbH, Kbb, Abb, Mfull);
    vtrans_kernel<<<dim3(2, NB, 9), 256, 0, stream>>>(Abb, VtB);
    attn_mfma_kernel<<<dim3(9, 2, NB), 256, 0, stream>>>(QbH, Kbb, VtB, Abb);
    bgemm_kernel<OP_ADDTO, true, true><<<dim3(4, 129), 256, 0, stream>>>(
        Abb, wpw + (size_t)l * 262144, X, Xb, Mfull, 512, 512, 512, 512);
    // FF split over hidden dim: two halves of 1024, full-M grids
    for (int hh = 0; hh < 2; ++hh) {
      bgemm_kernel<OP_GELU, false, true><<<dim3(8, 129), 256, 0, stream>>>(
          Xb, wf1 + (size_t)l * 1048576 + (size_t)hh * 1024 * 512, nullptr, Hb,
          Mfull, 1024, 512, 512, 512);
      if (hh == 0)
        bgemm_kernel<OP_ADDTO, true, false><<<dim3(4, 129), 256, 0, stream>>>(
            Hb, wf2 + (size_t)l * 1048576, X, nullptr,
            Mfull, 512, 1024, 1024, 2048);
      else
        bgemm_kernel<OP_ADDTO, true, true><<<dim3(4, 129), 256, 0, stream>>>(
            Hb, wf2 + (size_t)l * 1048576 + 1024, X, Xb,
            Mfull, 512, 1024, 1024, 2048);
    }
  }

  // pooling head: fused K|V projection into Hb [M][1024], then block-per-(h,b)
  bgemm_kernel<OP_NONE, false, true><<<dim3(8, 129), 256, 0, stream>>>(
      Xb, wpkv, nullptr, Hb, Mfull, 1024, 512, 512, 512);
  pool_kernel<<<dim3(8, NB), 256, 0, stream>>>(Hb, pq, Pb);

  // small head MLP stack: split-K skinny GEMMs; partial-sum+GELU fused into
  // the consumer's A-load (cross-dispatch ordering provides visibility).
  skgemm_kernel<OP_NONE, 1><<<dim3(8, 8), 256, 0, stream>>>(
      Pb, ppw, CpA, 512, 512);
  ln_kernel<<<NB, 256, 0, stream>>>(CpA, Xg);   // Xg = LN(sum_k CpA)
  for (int l = 0; l < 4; ++l) {
    skgemm_kernel<OP_NONE, 1><<<dim3(32, 8), 256, 0, stream>>>(
        Xg, g1 + (size_t)l * 2048 * 512, CpA, 2048, 512);
    // A = GELU(sum_k CpA)  (fused), output partials -> CpB
    skgemm_kernel<OP_GELU, 8><<<dim3(8, 32), 256, 0, stream>>>(
        CpA, g2 + (size_t)l * 512 * 2048, CpB, 512, 2048);
    sred_kernel<OP_ADDTO><<<64, 256, 0, stream>>>(CpB, Xg, 512, 32);
  }
  skgemm_kernel<OP_NONE, 1><<<dim3(32, 8), 256, 0, stream>>>(
      Xg, ow1, CpA, 2048, 512);
  skgemm_kernel<OP_GELU, 8><<<dim3(16, 32), 256, 0, stream>>>(
      CpA, ow2, CpB, 1024, 2048);
  sred_kernel<OP_NONE><<<128, 256, 0, stream>>>(CpB, out, 1024, 32);
}